// Round 1
// baseline (803.872 us; speedup 1.0000x reference)
//
#include <hip/hip_runtime.h>

#define DEVI static __device__ __forceinline__

constexpr int B_ = 2, C_ = 128, H_ = 128, W_ = 256;
constexpr int NW_ = 4, CG_ = 32, MD_ = 96;
constexpr int HW_ = H_ * W_;        // 32768
constexpr int CHW_ = C_ * HW_;      // 4194304
constexpr int TEN_ = B_ * CHW_;     // 8388608 elements per tensor

// ---------------- weight transpose: Wt[k][o] = W[o][k] ----------------
struct WtPack { const float* s[6]; float* d[6]; };

__global__ __launch_bounds__(256) void k_wt(WtPack p) {
  int m = blockIdx.y;
  int idx = blockIdx.x * 256 + threadIdx.x;   // 0..16383
  int o = idx >> 7, k = idx & 127;
  p.d[m][k * 128 + o] = p.s[m][idx];
}

// ---------------- depthwise 3x3 + bias (SAME, zero pad) ----------------
__global__ __launch_bounds__(256) void k_dw(
    const float* __restrict__ xl, const float* __restrict__ xr,
    const float* __restrict__ wd, const float* __restrict__ bd,
    float* __restrict__ ol, float* __restrict__ orr) {
  const float* x = blockIdx.y ? xr : xl;
  float* o = blockIdx.y ? orr : ol;
  int idx = blockIdx.x * 256 + threadIdx.x;
  int w = idx & (W_ - 1);
  int h = (idx >> 8) & (H_ - 1);
  int c = (idx >> 15) & (C_ - 1);
  const float* wp = wd + c * 9;
  const float* xb = x + (idx - (idx & (HW_ - 1)));   // (b,c) plane start
  float acc = bd[c];
#pragma unroll
  for (int dy = -1; dy <= 1; ++dy) {
    int hh = h + dy;
    if (hh < 0 || hh >= H_) continue;
    const float* row = xb + hh * W_;
    const float* wr = wp + (dy + 1) * 3;
    if (w > 0) acc += wr[0] * row[w - 1];
    acc += wr[1] * row[w];
    if (w < W_ - 1) acc += wr[2] * row[w + 1];
  }
  o[idx] = acc;
}

// ---------------- conv1x1 tiled GEMM ----------------
// block = 256 thr, tile = 64 pixels (one h row, w0..w0+63) x all 128 out ch.
// Xs[128][64] staged in LDS (with optional feature-shift), Wt read from global
// (64 KB, L1/L2 resident). Thread computes 8 o x 4 p.
template <bool SHIFT, bool HAS_BIAS, bool HAS_RESID, bool DO_LN>
__global__ __launch_bounds__(256) void k_conv(
    const float* __restrict__ X, const float* __restrict__ Wt,
    const float* __restrict__ bias, const float* __restrict__ resid,
    const float* __restrict__ lnw, const float* __restrict__ lnb,
    float* __restrict__ out) {
  __shared__ float Xs[128][64];
  __shared__ float red[DO_LN ? 2176 : 4];
  int t = threadIdx.x;
  int bid = blockIdx.x;                 // B*H*4 = 1024
  int b = bid >> 9;
  int h = (bid >> 2) & (H_ - 1);
  int w0 = (bid & 3) << 6;
  int lane = t & 63, ci = t >> 6;
  int wg = w0 + lane;
#pragma unroll
  for (int r = 0; r < 32; ++r) {
    int i = ci * 32 + r;
    float v;
    if (SHIFT) {
      int g = i >> 4;
      int hh = h, ww = wg;
      bool ok = true;
      if (g == 0)      { ww = wg + 1; ok = ww < W_; }
      else if (g == 1) { ww = wg - 1; ok = ww >= 0; }
      else if (g == 2) { hh = h + 1;  ok = hh < H_; }
      else if (g == 3) { hh = h - 1;  ok = hh >= 0; }
      v = ok ? X[((b * C_ + i) * H_ + hh) * W_ + ww] : 0.0f;
    } else {
      v = X[((b * C_ + i) * H_ + h) * W_ + wg];
    }
    Xs[i][lane] = v;
  }
  __syncthreads();
  int po = (t & 15) << 2;        // pixel 0..60
  int oo = (t >> 4) << 3;        // out-ch 0..120
  float acc[8][4];
#pragma unroll
  for (int a = 0; a < 8; ++a)
#pragma unroll
    for (int p = 0; p < 4; ++p) acc[a][p] = 0.0f;
#pragma unroll 4
  for (int k = 0; k < 128; ++k) {
    float4 xv = *(const float4*)&Xs[k][po];
    float xa[4] = {xv.x, xv.y, xv.z, xv.w};
    float4 wa = *(const float4*)(Wt + (k << 7) + oo);
    float4 wb = *(const float4*)(Wt + (k << 7) + oo + 4);
    float wz[8] = {wa.x, wa.y, wa.z, wa.w, wb.x, wb.y, wb.z, wb.w};
#pragma unroll
    for (int a = 0; a < 8; ++a)
#pragma unroll
      for (int p = 0; p < 4; ++p) acc[a][p] += wz[a] * xa[p];
  }
  if (HAS_BIAS) {
#pragma unroll
    for (int a = 0; a < 8; ++a) {
      float bb = bias[oo + a];
#pragma unroll
      for (int p = 0; p < 4; ++p) acc[a][p] += bb;
    }
  }
  if (HAS_RESID) {
#pragma unroll
    for (int a = 0; a < 8; ++a) {
      float4 rv = *(const float4*)(resid + (b * C_ + oo + a) * HW_ + h * W_ + w0 + po);
      acc[a][0] += rv.x; acc[a][1] += rv.y; acc[a][2] += rv.z; acc[a][3] += rv.w;
    }
  }
  if (DO_LN) {
    float* redS = red;
    float* redQ = red + 1024;
    float* muS  = red + 2048;
    float* rsS  = red + 2112;
    float s[4] = {0, 0, 0, 0}, q[4] = {0, 0, 0, 0};
#pragma unroll
    for (int a = 0; a < 8; ++a)
#pragma unroll
      for (int p = 0; p < 4; ++p) { s[p] += acc[a][p]; q[p] += acc[a][p] * acc[a][p]; }
    int g = t >> 4;
    *(float4*)&redS[g * 64 + po] = make_float4(s[0], s[1], s[2], s[3]);
    *(float4*)&redQ[g * 64 + po] = make_float4(q[0], q[1], q[2], q[3]);
    __syncthreads();
    if (t < 64) {
      float ss = 0.f, qq = 0.f;
#pragma unroll
      for (int g2 = 0; g2 < 16; ++g2) { ss += redS[g2 * 64 + t]; qq += redQ[g2 * 64 + t]; }
      float mu = ss * (1.0f / 128.0f);
      float var = qq * (1.0f / 128.0f) - mu * mu;   // biased var
      muS[t] = mu;
      rsS[t] = rsqrtf(var + 1e-6f);
    }
    __syncthreads();
#pragma unroll
    for (int a = 0; a < 8; ++a) {
      float lw = lnw[oo + a], lb = lnb[oo + a];
#pragma unroll
      for (int p = 0; p < 4; ++p)
        acc[a][p] = lw * ((acc[a][p] - muS[po + p]) * rsS[po + p]) + lb;
    }
  }
#pragma unroll
  for (int a = 0; a < 8; ++a) {
    *(float4*)(out + (b * C_ + oo + a) * HW_ + h * W_ + w0 + po) =
        make_float4(acc[a][0], acc[a][1], acc[a][2], acc[a][3]);
  }
}

// ---------------- per-(b,k,h,c) row sums of vl / vr ----------------
__global__ __launch_bounds__(256) void k_sv(
    const float* __restrict__ vl, const float* __restrict__ vr,
    float* __restrict__ svl, float* __restrict__ svr) {
  int gw = (blockIdx.x * 256 + threadIdx.x) >> 6;   // global wave id, 2048 waves
  int lane = threadIdx.x & 63;
  for (int r = 0; r < 64; ++r) {
    int row = gw * 64 + r;                  // 0..131071
    int arr = row >> 16;
    int rem = row & 65535;                  // = bk*4096 + h*32 + c
    int c = rem & 31;
    int h = (rem >> 5) & 127;
    int bk = rem >> 12;
    const float* src = arr ? vr : vl;
    const float4* p4 =
        (const float4*)(src + ((bk >> 2) * C_ + (bk & 3) * CG_ + c) * HW_ + h * W_) + lane;
    float4 v = *p4;
    float s = v.x + v.y + v.z + v.w;
#pragma unroll
    for (int off = 32; off > 0; off >>= 1) s += __shfl_down(s, off);
    if (lane == 0) (arr ? svr : svl)[rem] = s;
  }
}

// ---------------- attention helpers ----------------
DEVI unsigned short f2b(float f) {
  unsigned u = __float_as_uint(f);
  return (unsigned short)((u + 0x7fffu + ((u >> 16) & 1u)) >> 16);   // RNE bf16
}
DEVI unsigned pk2(float a, float b) {
  return (unsigned)f2b(a) | ((unsigned)f2b(b) << 16);
}
DEVI float blo(unsigned u) { return __uint_as_float(u << 16); }
DEVI float bhi(unsigned u) { return __uint_as_float(u & 0xffff0000u); }

// LDS row layout: [j][16 u32] = 32 bf16; oct-XOR swizzle for conflict-free
// per-lane b128 column reads: oct' = o ^ (j&3) ^ ((j>>2)&3)
DEVI void ldrow32(const unsigned* A, int u, float* o32) {
#pragma unroll
  for (int o = 0; o < 4; ++o) {
    int oc = o ^ (u & 3) ^ ((u >> 2) & 3);
    uint4 kv = *(const uint4*)(A + u * 16 + oc * 4);
    o32[o * 8 + 0] = blo(kv.x); o32[o * 8 + 1] = bhi(kv.x);
    o32[o * 8 + 2] = blo(kv.y); o32[o * 8 + 3] = bhi(kv.y);
    o32[o * 8 + 4] = blo(kv.z); o32[o * 8 + 5] = bhi(kv.z);
    o32[o * 8 + 6] = blo(kv.w); o32[o * 8 + 7] = bhi(kv.w);
  }
}

DEVI void stage32(const float* __restrict__ G, unsigned* A, int t) {
#pragma unroll
  for (int o = 0; o < 4; ++o) {
    float f0 = G[(8 * o + 0) * HW_ + t];
    float f1 = G[(8 * o + 1) * HW_ + t];
    float f2 = G[(8 * o + 2) * HW_ + t];
    float f3 = G[(8 * o + 3) * HW_ + t];
    float f4 = G[(8 * o + 4) * HW_ + t];
    float f5 = G[(8 * o + 5) * HW_ + t];
    float f6 = G[(8 * o + 6) * HW_ + t];
    float f7 = G[(8 * o + 7) * HW_ + t];
    int oc = o ^ (t & 3) ^ ((t >> 2) & 3);
    *(uint4*)(A + t * 16 + oc * 4) =
        make_uint4(pk2(f0, f1), pk2(f2, f3), pk2(f4, f5), pk2(f6, f7));
  }
}

// ---------------- banded cross attention (both directions) ----------------
// One block per (b, k, h). Softmax includes masked entries as value 0
// (torch semantics: atn = raw*mask then softmax). Closed form via Sv.
__global__ __launch_bounds__(256) void k_attn(
    const float* __restrict__ ql, const float* __restrict__ qr,
    const float* __restrict__ vl, const float* __restrict__ vr,
    const float* __restrict__ svl, const float* __restrict__ svr,
    float* __restrict__ outL, float* __restrict__ outR) {
  __shared__ unsigned Kl[256 * 16];
  __shared__ unsigned Kr[256 * 16];
  __shared__ unsigned Vl[256 * 16];
  __shared__ unsigned Vr[256 * 16];
  int t = threadIdx.x;
  int bid = blockIdx.x;                 // 1024 = B*NW*H
  int b = bid >> 9, k4 = (bid >> 7) & 3, h = bid & 127;
  int base = b * CHW_ + k4 * CG_ * HW_ + h * W_;
  int svb = (((b << 2) | k4) << 12) | (h << 5);
  stage32(ql + base, Kl, t);
  stage32(qr + base, Kr, t);
  stage32(vl + base, Vl, t);
  stage32(vr + base, Vr, t);
  __syncthreads();

  // ---- phase L: thread = row i=t, softmax over j (warpL) ----
  {
    float qreg[32];
#pragma unroll
    for (int c = 0; c < 32; ++c) qreg[c] = ql[base + c * HW_ + t];
    float m = 0.0f;                               // masked zeros participate
    for (int d = 0; d <= MD_; ++d) {
      int u = t - d;
      if (u >= 0) {
        float row[32]; ldrow32(Kr, u, row);
        float dot = 0.f;
#pragma unroll
        for (int c = 0; c < 32; ++c) dot += qreg[c] * row[c];
        m = fmaxf(m, dot);
      }
    }
    float em = __expf(-m);
    float l = 256.0f * em;
    float acc[32];
#pragma unroll
    for (int c = 0; c < 32; ++c) acc[c] = em * svr[svb + c];
    for (int d = 0; d <= MD_; ++d) {
      int u = t - d;
      if (u >= 0) {
        float row[32]; ldrow32(Kr, u, row);
        float dot = 0.f;
#pragma unroll
        for (int c = 0; c < 32; ++c) dot += qreg[c] * row[c];
        float wgt = __expf(dot - m) - em;
        l += wgt;
        float vrow[32]; ldrow32(Vr, u, vrow);
#pragma unroll
        for (int c = 0; c < 32; ++c) acc[c] += wgt * vrow[c];
      }
    }
    float rl = 1.0f / l;
#pragma unroll
    for (int c = 0; c < 32; ++c) outL[base + c * HW_ + t] = acc[c] * rl;
  }

  // ---- phase R: thread = col j=t, softmax over i (warpR) ----
  {
    float qreg[32];
#pragma unroll
    for (int c = 0; c < 32; ++c) qreg[c] = qr[base + c * HW_ + t];
    float m = 0.0f;
    for (int d = 0; d <= MD_; ++d) {
      int u = t + d;
      if (u < W_) {
        float row[32]; ldrow32(Kl, u, row);
        float dot = 0.f;
#pragma unroll
        for (int c = 0; c < 32; ++c) dot += qreg[c] * row[c];
        m = fmaxf(m, dot);
      }
    }
    float em = __expf(-m);
    float l = 256.0f * em;
    float acc[32];
#pragma unroll
    for (int c = 0; c < 32; ++c) acc[c] = em * svl[svb + c];
    for (int d = 0; d <= MD_; ++d) {
      int u = t + d;
      if (u < W_) {
        float row[32]; ldrow32(Kl, u, row);
        float dot = 0.f;
#pragma unroll
        for (int c = 0; c < 32; ++c) dot += qreg[c] * row[c];
        float wgt = __expf(dot - m) - em;
        l += wgt;
        float vrow[32]; ldrow32(Vl, u, vrow);
#pragma unroll
        for (int c = 0; c < 32; ++c) acc[c] += wgt * vrow[c];
      }
    }
    float rl = 1.0f / l;
#pragma unroll
    for (int c = 0; c < 32; ++c) outR[base + c * HW_ + t] = acc[c] * rl;
  }
}

// ---------------- launch ----------------
extern "C" void kernel_launch(void* const* d_in, const int* in_sizes, int n_in,
                              void* d_out, int out_size, void* d_ws, size_t ws_size,
                              hipStream_t stream) {
  const float* xl0    = (const float*)d_in[0];
  const float* xr0    = (const float*)d_in[1];
  const float* ln_l_w = (const float*)d_in[2];
  const float* ln_l_b = (const float*)d_in[3];
  const float* ln_r_w = (const float*)d_in[4];
  const float* ln_r_b = (const float*)d_in[5];
  const float* feaL_w = (const float*)d_in[6];
  const float* feaR_w = (const float*)d_in[7];
  const float* to_l_w = (const float*)d_in[8];
  const float* to_r_w = (const float*)d_in[9];
  const float* td_w   = (const float*)d_in[10];
  const float* td_b   = (const float*)d_in[11];
  const float* tp_w   = (const float*)d_in[12];
  const float* tp_b   = (const float*)d_in[13];
  const float* out_w  = (const float*)d_in[14];

  float* o0 = (float*)d_out;          // left tensor (also scratch: dw_l, ql)
  float* o1 = o0 + TEN_;              // right tensor (dw_r, qr)
  float* ws = (float*)d_ws;
  float* b0 = ws;                     // xleft -> vl
  float* b1 = ws + TEN_;              // xright -> vr
  float* wt = ws + 2 * (size_t)TEN_;  // 6 x 16384 transposed weights
  float* wt_feaL = wt + 0 * 16384;
  float* wt_feaR = wt + 1 * 16384;
  float* wt_tol  = wt + 2 * 16384;
  float* wt_tor  = wt + 3 * 16384;
  float* wt_tp   = wt + 4 * 16384;
  float* wt_out  = wt + 5 * 16384;
  float* svl = wt + 6 * 16384;        // 65536 each
  float* svr = svl + 65536;

  WtPack pk;
  pk.s[0] = feaL_w; pk.s[1] = feaR_w; pk.s[2] = to_l_w;
  pk.s[3] = to_r_w; pk.s[4] = tp_w;   pk.s[5] = out_w;
  pk.d[0] = wt_feaL; pk.d[1] = wt_feaR; pk.d[2] = wt_tol;
  pk.d[3] = wt_tor;  pk.d[4] = wt_tp;   pk.d[5] = wt_out;
  k_wt<<<dim3(64, 6), 256, 0, stream>>>(pk);

  // dwconv3x3 -> d_out scratch
  k_dw<<<dim3(TEN_ / 256, 2), 256, 0, stream>>>(xl0, xr0, td_w, td_b, o0, o1);

  // transition conv + bias + residual + LN -> xleft/xright
  k_conv<false, true, true, true><<<1024, 256, 0, stream>>>(
      o0, wt_tp, tp_b, xl0, ln_l_w, ln_l_b, b0);
  k_conv<false, true, true, true><<<1024, 256, 0, stream>>>(
      o1, wt_tp, tp_b, xr0, ln_r_w, ln_r_b, b1);

  // Q projections on shifted LN output -> d_out scratch
  k_conv<true, false, false, false><<<1024, 256, 0, stream>>>(
      b0, wt_tol, nullptr, nullptr, nullptr, nullptr, o0);
  k_conv<true, false, false, false><<<1024, 256, 0, stream>>>(
      b1, wt_tor, nullptr, nullptr, nullptr, nullptr, o1);

  // V projections on shifted original inputs -> b0/b1
  k_conv<true, false, false, false><<<1024, 256, 0, stream>>>(
      xl0, wt_feaL, nullptr, nullptr, nullptr, nullptr, b0);
  k_conv<true, false, false, false><<<1024, 256, 0, stream>>>(
      xr0, wt_feaR, nullptr, nullptr, nullptr, nullptr, b1);

  // V row sums (masked-softmax closed form)
  k_sv<<<512, 256, 0, stream>>>(b0, b1, svl, svr);

  // attention: warpL -> o0 (over ql), warpR -> o1 (over qr); per-block in-place safe
  k_attn<<<1024, 256, 0, stream>>>(o0, o1, b0, b1, svl, svr, o0, o1);

  // final conv + residual, in-place on d_out (tile staged in LDS before write)
  k_conv<false, false, true, false><<<1024, 256, 0, stream>>>(
      o0, wt_out, nullptr, xl0, nullptr, nullptr, o0);
  k_conv<false, false, true, false><<<1024, 256, 0, stream>>>(
      o1, wt_out, nullptr, xr0, nullptr, nullptr, o1);
}

// Round 2
// 535.742 us; speedup vs baseline: 1.5005x; 1.5005x over previous
//
#include <hip/hip_runtime.h>

#define DEVI static __device__ __forceinline__

constexpr int B_ = 2, C_ = 128, H_ = 128, W_ = 256;
constexpr int CG_ = 32, MD_ = 96;
constexpr int HW_ = H_ * W_;        // 32768
constexpr int CHW_ = C_ * HW_;      // 4194304
constexpr int TEN_ = B_ * CHW_;     // 8388608 elements per tensor

typedef short bf16x8 __attribute__((ext_vector_type(8)));
typedef float f32x16 __attribute__((ext_vector_type(16)));

// ---------------- weight transpose: Wt[k][o] = W[o][k] ----------------
struct WtPack { const float* s[6]; float* d[6]; };

__global__ __launch_bounds__(256) void k_wt(WtPack p) {
  int m = blockIdx.y;
  int idx = blockIdx.x * 256 + threadIdx.x;   // 0..16383
  int o = idx >> 7, k = idx & 127;
  p.d[m][k * 128 + o] = p.s[m][idx];
}

// ---------------- depthwise 3x3 + bias (SAME, zero pad) ----------------
__global__ __launch_bounds__(256) void k_dw(
    const float* __restrict__ xl, const float* __restrict__ xr,
    const float* __restrict__ wd, const float* __restrict__ bd,
    float* __restrict__ ol, float* __restrict__ orr) {
  const float* x = blockIdx.y ? xr : xl;
  float* o = blockIdx.y ? orr : ol;
  int idx = blockIdx.x * 256 + threadIdx.x;
  int w = idx & (W_ - 1);
  int h = (idx >> 8) & (H_ - 1);
  int c = (idx >> 15) & (C_ - 1);
  const float* wp = wd + c * 9;
  const float* xb = x + (idx - (idx & (HW_ - 1)));   // (b,c) plane start
  float acc = bd[c];
#pragma unroll
  for (int dy = -1; dy <= 1; ++dy) {
    int hh = h + dy;
    if (hh < 0 || hh >= H_) continue;
    const float* row = xb + hh * W_;
    const float* wr = wp + (dy + 1) * 3;
    if (w > 0) acc += wr[0] * row[w - 1];
    acc += wr[1] * row[w];
    if (w < W_ - 1) acc += wr[2] * row[w + 1];
  }
  o[idx] = acc;
}

// ---------------- conv1x1 tiled GEMM (f32 VALU) ----------------
template <bool SHIFT, bool HAS_BIAS, bool HAS_RESID, bool DO_LN>
__global__ __launch_bounds__(256) void k_conv(
    const float* __restrict__ X, const float* __restrict__ Wt,
    const float* __restrict__ bias, const float* __restrict__ resid,
    const float* __restrict__ lnw, const float* __restrict__ lnb,
    float* __restrict__ out) {
  __shared__ __align__(16) float Xs[128][64];
  __shared__ __align__(16) float red[DO_LN ? 2176 : 4];
  int t = threadIdx.x;
  int bid = blockIdx.x;                 // B*H*4 = 1024
  int b = bid >> 9;
  int h = (bid >> 2) & (H_ - 1);
  int w0 = (bid & 3) << 6;
  int lane = t & 63, ci = t >> 6;
  int wg = w0 + lane;
#pragma unroll
  for (int r = 0; r < 32; ++r) {
    int i = ci * 32 + r;
    float v;
    if (SHIFT) {
      int g = i >> 4;
      int hh = h, ww = wg;
      bool ok = true;
      if (g == 0)      { ww = wg + 1; ok = ww < W_; }
      else if (g == 1) { ww = wg - 1; ok = ww >= 0; }
      else if (g == 2) { hh = h + 1;  ok = hh < H_; }
      else if (g == 3) { hh = h - 1;  ok = hh >= 0; }
      v = ok ? X[((b * C_ + i) * H_ + hh) * W_ + ww] : 0.0f;
    } else {
      v = X[((b * C_ + i) * H_ + h) * W_ + wg];
    }
    Xs[i][lane] = v;
  }
  __syncthreads();
  int po = (t & 15) << 2;        // pixel 0..60
  int oo = (t >> 4) << 3;        // out-ch 0..120
  float acc[8][4];
#pragma unroll
  for (int a = 0; a < 8; ++a)
#pragma unroll
    for (int p = 0; p < 4; ++p) acc[a][p] = 0.0f;
#pragma unroll 4
  for (int k = 0; k < 128; ++k) {
    float4 xv = *(const float4*)&Xs[k][po];
    float xa[4] = {xv.x, xv.y, xv.z, xv.w};
    float4 wa = *(const float4*)(Wt + (k << 7) + oo);
    float4 wb = *(const float4*)(Wt + (k << 7) + oo + 4);
    float wz[8] = {wa.x, wa.y, wa.z, wa.w, wb.x, wb.y, wb.z, wb.w};
#pragma unroll
    for (int a = 0; a < 8; ++a)
#pragma unroll
      for (int p = 0; p < 4; ++p) acc[a][p] += wz[a] * xa[p];
  }
  if (HAS_BIAS) {
#pragma unroll
    for (int a = 0; a < 8; ++a) {
      float bb = bias[oo + a];
#pragma unroll
      for (int p = 0; p < 4; ++p) acc[a][p] += bb;
    }
  }
  if (HAS_RESID) {
#pragma unroll
    for (int a = 0; a < 8; ++a) {
      float4 rv = *(const float4*)(resid + (b * C_ + oo + a) * HW_ + h * W_ + w0 + po);
      acc[a][0] += rv.x; acc[a][1] += rv.y; acc[a][2] += rv.z; acc[a][3] += rv.w;
    }
  }
  if (DO_LN) {
    float* redS = red;
    float* redQ = red + 1024;
    float* muS  = red + 2048;
    float* rsS  = red + 2112;
    float s[4] = {0, 0, 0, 0}, q[4] = {0, 0, 0, 0};
#pragma unroll
    for (int a = 0; a < 8; ++a)
#pragma unroll
      for (int p = 0; p < 4; ++p) { s[p] += acc[a][p]; q[p] += acc[a][p] * acc[a][p]; }
    int g = t >> 4;
    *(float4*)&redS[g * 64 + po] = make_float4(s[0], s[1], s[2], s[3]);
    *(float4*)&redQ[g * 64 + po] = make_float4(q[0], q[1], q[2], q[3]);
    __syncthreads();
    if (t < 64) {
      float ss = 0.f, qq = 0.f;
#pragma unroll
      for (int g2 = 0; g2 < 16; ++g2) { ss += redS[g2 * 64 + t]; qq += redQ[g2 * 64 + t]; }
      float mu = ss * (1.0f / 128.0f);
      float var = qq * (1.0f / 128.0f) - mu * mu;   // biased var
      muS[t] = mu;
      rsS[t] = rsqrtf(var + 1e-6f);
    }
    __syncthreads();
#pragma unroll
    for (int a = 0; a < 8; ++a) {
      float lw = lnw[oo + a], lb = lnb[oo + a];
#pragma unroll
      for (int p = 0; p < 4; ++p)
        acc[a][p] = lw * ((acc[a][p] - muS[po + p]) * rsS[po + p]) + lb;
    }
  }
#pragma unroll
  for (int a = 0; a < 8; ++a) {
    *(float4*)(out + (b * C_ + oo + a) * HW_ + h * W_ + w0 + po) =
        make_float4(acc[a][0], acc[a][1], acc[a][2], acc[a][3]);
  }
}

// ---------------- bf16 helpers ----------------
DEVI unsigned short f2b(float f) {
  unsigned u = __float_as_uint(f);
  return (unsigned short)((u + 0x7fffu + ((u >> 16) & 1u)) >> 16);   // RNE bf16
}
DEVI unsigned pk2(float a, float b) {
  return (unsigned)f2b(a) | ((unsigned)f2b(b) << 16);
}

// ============ MFMA attention (32x32x16 bf16) ============
// Q layout in LDS: [pos 0..255][32 ch bf16] rows of 64B; 16B clusters
// swizzled: cl' = cl ^ ((pos>>1)&3)  -> min-conflict b128 frag reads.
// V layout: [ch 0..31][256 pos bf16] rows of 512B; 16B clusters (8 pos)
// swizzled: jc' = jc ^ (ch&7).

DEVI bf16x8 ldfrag(const unsigned* A, int r, int cl) {
  int clp = cl ^ ((r >> 1) & 3);
  uint4 v = *(const uint4*)(A + r * 16 + clp * 4);
  return __builtin_bit_cast(bf16x8, v);
}

DEVI bf16x8 vfrag(const unsigned* Vt, int c, int ktg, int hi) {
  int jc = 2 * ktg + hi;
  int jcp = jc ^ (c & 7);
  uint4 v = *(const uint4*)(Vt + c * 128 + jcp * 4);
  return __builtin_bit_cast(bf16x8, v);
}

DEVI void stageQ(const float* __restrict__ G, unsigned* A, int t) {
  unsigned row[16];
#pragma unroll
  for (int c = 0; c < 16; ++c)
    row[c] = pk2(G[(2 * c) * HW_ + t], G[(2 * c + 1) * HW_ + t]);
  int sw = (t >> 1) & 3;
#pragma unroll
  for (int cl = 0; cl < 4; ++cl) {
    int clp = cl ^ sw;
    *(uint4*)(A + t * 16 + clp * 4) =
        make_uint4(row[cl * 4], row[cl * 4 + 1], row[cl * 4 + 2], row[cl * 4 + 3]);
  }
}

// stages V (bf16, transposed layout) + per-32-tile channel sums psv[jt][c]
DEVI void stageV(const float* __restrict__ G, unsigned* Vt, float* psv, int t) {
  int c = t >> 3, jb = t & 7;
  const float* src = G + c * HW_ + jb * 32;
  float sum = 0.f;
#pragma unroll
  for (int qd = 0; qd < 4; ++qd) {
    float4 a = *(const float4*)(src + qd * 8);
    float4 bq = *(const float4*)(src + qd * 8 + 4);
    sum += a.x + a.y + a.z + a.w + bq.x + bq.y + bq.z + bq.w;
    int jc = jb * 4 + qd;
    int jcp = jc ^ (c & 7);
    *(uint4*)(Vt + c * 128 + jcp * 4) =
        make_uint4(pk2(a.x, a.y), pk2(a.z, a.w), pk2(bq.x, bq.y), pk2(bq.z, bq.w));
  }
  psv[jb * 32 + c] = sum;
}

// One attention direction. DIR=0 (L): keys j in [q-96, q]. DIR=1 (R): keys in [q, q+96].
// D = mfma(A=Qk, B=Qq): D[key][query]; col(lane&31) = query -> lane-local softmax.
template <int DIR>
DEVI void attn_pass(const unsigned* Ql_, const unsigned* Qk_, const unsigned* Vt,
                    const float* psv, float* emr, float* __restrict__ outG,
                    int wid, int lane) {
  int hi = lane >> 5, cq = lane & 31;
#pragma unroll
  for (int s = 0; s < 2; ++s) {
    int qt = 2 * wid + s;
    int q = qt * 32 + cq;
    int jt0 = DIR ? qt : (qt >= 3 ? qt - 3 : 0);
    int jt1 = DIR ? (qt <= 4 ? qt + 3 : 7) : qt;
    int nt = jt1 - jt0 + 1;                      // wave-uniform (1..4)
    bf16x8 bq0 = ldfrag(Ql_, q, hi);             // query B-frag kt=0
    bf16x8 bq1 = ldfrag(Ql_, q, hi + 2);         // kt=1
    f32x16 S[4];
#pragma unroll
    for (int ji = 0; ji < 4; ++ji) {
      if (ji < nt) {
        int jt = jt0 + ji;
        f32x16 d = {};
        d = __builtin_amdgcn_mfma_f32_32x32x16_bf16(
            ldfrag(Qk_, jt * 32 + cq, hi), bq0, d, 0, 0, 0);
        d = __builtin_amdgcn_mfma_f32_32x32x16_bf16(
            ldfrag(Qk_, jt * 32 + cq, hi + 2), bq1, d, 0, 0, 0);
        S[ji] = d;
      }
    }
    // mask (multiplicative: masked -> 0, participates in softmax) + row max
    float m = 0.f;
#pragma unroll
    for (int ji = 0; ji < 4; ++ji) if (ji < nt) {
      int jb = (jt0 + ji) * 32 + 4 * hi;
#pragma unroll
      for (int r = 0; r < 16; ++r) {
        int j = jb + (r & 3) + 8 * (r >> 2);     // verified C/D row mapping
        bool act = DIR ? (j >= q && j <= q + MD_) : (j <= q && j >= q - MD_);
        float v = act ? S[ji][r] : 0.f;
        S[ji][r] = v;
        m = fmaxf(m, v);
      }
    }
    m = fmaxf(m, __shfl_xor(m, 32));
    float em_ = __expf(-m);
    float lsum = 0.f;
#pragma unroll
    for (int ji = 0; ji < 4; ++ji) if (ji < nt) {
#pragma unroll
      for (int r = 0; r < 16; ++r) {
        float e = __expf(S[ji][r] - m);
        S[ji][r] = e;
        lsum += e;
      }
    }
    lsum += __shfl_xor(lsum, 32);
    lsum += (float)((8 - nt) * 32) * em_;        // skipped all-masked tiles
    float rl = 1.f / lsum;
    if (hi == 0) { emr[qt * 32 + cq] = em_; emr[256 + qt * 32 + cq] = rl; }
    // PV: in-register E -> A-frags via pk2 + shfl_xor(32) half-exchange
    f32x16 acc = {};
#pragma unroll
    for (int ji = 0; ji < 4; ++ji) if (ji < nt) {
      int jt = jt0 + ji;
      unsigned x[8], ox[8];
#pragma unroll
      for (int w2 = 0; w2 < 8; ++w2) x[w2] = pk2(S[ji][2 * w2], S[ji][2 * w2 + 1]);
#pragma unroll
      for (int w2 = 0; w2 < 8; ++w2) ox[w2] = __shfl_xor(x[w2], 32);
#pragma unroll
      for (int hf = 0; hf < 2; ++hf) {
        unsigned w0 = hi ? ox[4 * hf + 2] : x[4 * hf + 0];
        unsigned w1 = hi ? ox[4 * hf + 3] : x[4 * hf + 1];
        unsigned w2_ = hi ? x[4 * hf + 2] : ox[4 * hf + 0];
        unsigned w3 = hi ? x[4 * hf + 3] : ox[4 * hf + 1];
        uint4 aw = make_uint4(w0, w1, w2_, w3);
        acc = __builtin_amdgcn_mfma_f32_32x32x16_bf16(
            __builtin_bit_cast(bf16x8, aw), vfrag(Vt, cq, 2 * jt + hf, hi),
            acc, 0, 0, 0);
      }
    }
    // epilogue: add skipped-tile closed form e^{-m_q} * sum_skipped(V), normalize
    float Rv = 0.f;
#pragma unroll
    for (int jt = 0; jt < 8; ++jt)
      if (jt < jt0 || jt > jt1) Rv += psv[jt * 32 + cq];
#pragma unroll
    for (int r = 0; r < 16; ++r) {
      int qr_ = (r & 3) + 8 * (r >> 2) + 4 * hi;
      float emq = emr[qt * 32 + qr_];
      float rlq = emr[256 + qt * 32 + qr_];
      outG[cq * HW_ + qt * 32 + qr_] = (acc[r] + emq * Rv) * rlq;
    }
  }
}

__global__ __launch_bounds__(256) void k_attn(
    const float* __restrict__ ql, const float* __restrict__ qr,
    const float* __restrict__ vl, const float* __restrict__ vr,
    float* __restrict__ outL, float* __restrict__ outR) {
  __shared__ __align__(16) unsigned Ql[4096];
  __shared__ __align__(16) unsigned Qr[4096];
  __shared__ __align__(16) unsigned Vt[4096];
  __shared__ float psv[256];
  __shared__ float emr[512];
  int t = threadIdx.x;
  int bid = blockIdx.x;                 // 1024 = B*NW*H
  int b = bid >> 9, k4 = (bid >> 7) & 3, h = bid & 127;
  int base = b * CHW_ + k4 * CG_ * HW_ + h * W_;
  stageQ(ql + base, Ql, t);
  stageQ(qr + base, Qr, t);
  stageV(vr + base, Vt, psv, t);
  __syncthreads();
  int wid = t >> 6, lane = t & 63;
  attn_pass<0>(Ql, Qr, Vt, psv, emr, outL + base, wid, lane);
  __syncthreads();                      // pass L done with Vt/psv
  stageV(vl + base, Vt, psv, t);
  __syncthreads();
  attn_pass<1>(Qr, Ql, Vt, psv, emr, outR + base, wid, lane);
}

// ---------------- launch ----------------
extern "C" void kernel_launch(void* const* d_in, const int* in_sizes, int n_in,
                              void* d_out, int out_size, void* d_ws, size_t ws_size,
                              hipStream_t stream) {
  const float* xl0    = (const float*)d_in[0];
  const float* xr0    = (const float*)d_in[1];
  const float* ln_l_w = (const float*)d_in[2];
  const float* ln_l_b = (const float*)d_in[3];
  const float* ln_r_w = (const float*)d_in[4];
  const float* ln_r_b = (const float*)d_in[5];
  const float* feaL_w = (const float*)d_in[6];
  const float* feaR_w = (const float*)d_in[7];
  const float* to_l_w = (const float*)d_in[8];
  const float* to_r_w = (const float*)d_in[9];
  const float* td_w   = (const float*)d_in[10];
  const float* td_b   = (const float*)d_in[11];
  const float* tp_w   = (const float*)d_in[12];
  const float* tp_b   = (const float*)d_in[13];
  const float* out_w  = (const float*)d_in[14];

  float* o0 = (float*)d_out;          // left tensor (scratch: dw_l, ql)
  float* o1 = o0 + TEN_;              // right tensor (dw_r, qr)
  float* ws = (float*)d_ws;
  float* b0 = ws;                     // xleft -> vl
  float* b1 = ws + TEN_;              // xright -> vr
  float* wt = ws + 2 * (size_t)TEN_;  // 6 x 16384 transposed weights
  float* wt_feaL = wt + 0 * 16384;
  float* wt_feaR = wt + 1 * 16384;
  float* wt_tol  = wt + 2 * 16384;
  float* wt_tor  = wt + 3 * 16384;
  float* wt_tp   = wt + 4 * 16384;
  float* wt_out  = wt + 5 * 16384;

  WtPack pk;
  pk.s[0] = feaL_w; pk.s[1] = feaR_w; pk.s[2] = to_l_w;
  pk.s[3] = to_r_w; pk.s[4] = tp_w;   pk.s[5] = out_w;
  pk.d[0] = wt_feaL; pk.d[1] = wt_feaR; pk.d[2] = wt_tol;
  pk.d[3] = wt_tor;  pk.d[4] = wt_tp;   pk.d[5] = wt_out;
  k_wt<<<dim3(64, 6), 256, 0, stream>>>(pk);

  // dwconv3x3 -> d_out scratch
  k_dw<<<dim3(TEN_ / 256, 2), 256, 0, stream>>>(xl0, xr0, td_w, td_b, o0, o1);

  // transition conv + bias + residual + LN -> xleft/xright
  k_conv<false, true, true, true><<<1024, 256, 0, stream>>>(
      o0, wt_tp, tp_b, xl0, ln_l_w, ln_l_b, b0);
  k_conv<false, true, true, true><<<1024, 256, 0, stream>>>(
      o1, wt_tp, tp_b, xr0, ln_r_w, ln_r_b, b1);

  // Q projections on shifted LN output -> d_out scratch
  k_conv<true, false, false, false><<<1024, 256, 0, stream>>>(
      b0, wt_tol, nullptr, nullptr, nullptr, nullptr, o0);
  k_conv<true, false, false, false><<<1024, 256, 0, stream>>>(
      b1, wt_tor, nullptr, nullptr, nullptr, nullptr, o1);

  // V projections on shifted original inputs -> b0/b1
  k_conv<true, false, false, false><<<1024, 256, 0, stream>>>(
      xl0, wt_feaL, nullptr, nullptr, nullptr, nullptr, b0);
  k_conv<true, false, false, false><<<1024, 256, 0, stream>>>(
      xr0, wt_feaR, nullptr, nullptr, nullptr, nullptr, b1);

  // MFMA attention: warpL -> o0, warpR -> o1 (per-block in-place safe)
  k_attn<<<1024, 256, 0, stream>>>(o0, o1, b0, b1, o0, o1);

  // final conv + residual, in-place on d_out (tile staged in LDS before write)
  k_conv<false, false, true, false><<<1024, 256, 0, stream>>>(
      o0, wt_out, nullptr, xl0, nullptr, nullptr, o0);
  k_conv<false, false, true, false><<<1024, 256, 0, stream>>>(
      o1, wt_out, nullptr, xr0, nullptr, nullptr, o1);
}

// Round 3
// 392.235 us; speedup vs baseline: 2.0495x; 1.3659x over previous
//
#include <hip/hip_runtime.h>

#define DEVI static __device__ __forceinline__

constexpr int B_ = 2, C_ = 128, H_ = 128, W_ = 256;
constexpr int CG_ = 32, MD_ = 96;
constexpr int HW_ = H_ * W_;        // 32768
constexpr int CHW_ = C_ * HW_;      // 4194304
constexpr int TEN_ = B_ * CHW_;     // 8388608 elements per tensor

typedef short bf16x8 __attribute__((ext_vector_type(8)));
typedef float f32x16 __attribute__((ext_vector_type(16)));

// ---------------- bf16 helpers ----------------
DEVI unsigned short f2b(float f) {
  unsigned u = __float_as_uint(f);
  return (unsigned short)((u + 0x7fffu + ((u >> 16) & 1u)) >> 16);   // RNE bf16
}
DEVI unsigned pk2(float a, float b) {
  return (unsigned)f2b(a) | ((unsigned)f2b(b) << 16);
}

// ---------------- weight convert: Wb[o][k] bf16 (no transpose) ----------------
struct WbPack { const float* s[6]; unsigned short* d[6]; };

__global__ __launch_bounds__(256) void k_wb(WbPack p) {
  int m = blockIdx.y;
  int idx = blockIdx.x * 256 + threadIdx.x;   // 0..16383
  p.d[m][idx] = f2b(p.s[m][idx]);
}

// ================= MFMA conv1x1 (32x32x16 bf16) =================
// Tile: 64 px (one h row, w0..w0+63) x 128 out-ch. 4 waves; wave wid owns
// o-tile wid (32 out-ch), 2 p-tiles. LDS Xs[px][128ch bf16] rows of 256B,
// 16B clusters XOR-swizzled cl' = cl ^ (px&7) for uniform bank spread.
// A-frag (weights, in regs): lane holds W[o = wid*32 + (lane&31)][16kk+8hi..+7].
// B-frag: lane holds X[k-slice][p = pt*32 + (lane&31)].
// TRANS: staged value = dwconv3x3(X)+td_b (fused), then conv bias cb, resid, LN.
template <bool SHIFT, bool TRANS, bool RESID, bool LN>
__global__ __launch_bounds__(256) void k_cmf(
    const float* __restrict__ X0, const float* __restrict__ X1,
    const unsigned short* __restrict__ Wb0, const unsigned short* __restrict__ Wb1,
    const float* __restrict__ dww, const float* __restrict__ dwb,
    const float* __restrict__ cb,
    const float* __restrict__ R0, const float* __restrict__ R1,
    const float* __restrict__ lnw0, const float* __restrict__ lnb0,
    const float* __restrict__ lnw1, const float* __restrict__ lnb1,
    float* __restrict__ O0, float* __restrict__ O1) {
  __shared__ __align__(16) unsigned Xs[64 * 64];
  __shared__ float red[LN ? 640 : 4];
  int side = blockIdx.y;
  const float* X = side ? X1 : X0;
  const unsigned short* Wb = side ? Wb1 : Wb0;
  const float* R = side ? R1 : R0;
  const float* lnw = side ? lnw1 : lnw0;
  const float* lnb = side ? lnb1 : lnb0;
  float* O = side ? O1 : O0;
  int t = threadIdx.x;
  int bid = blockIdx.x;                 // 1024 = B*H*4
  int b = bid >> 9, h = (bid >> 2) & 127, w0 = (bid & 3) << 6;
  int lane = t & 63, wid = t >> 6, hi = lane >> 5, lr = lane & 31;

  // weight A-frags (register-resident, L1-hot global reads)
  bf16x8 wf[8];
  const unsigned short* wbase = Wb + (wid * 32 + lr) * 128 + hi * 8;
#pragma unroll
  for (int kk = 0; kk < 8; ++kk)
    wf[kk] = *(const bf16x8*)(wbase + kk * 16);

  // -------- stage input tile (px = t&63, channels cg*32..+31) --------
  int px = t & 63, cg = t >> 6;
  int wg = w0 + px;
  unsigned rb[16];
  if (TRANS) {
#pragma unroll
    for (int u = 0; u < 16; ++u) {
      float v[2];
#pragma unroll
      for (int e = 0; e < 2; ++e) {
        int c = cg * 32 + 2 * u + e;
        const float* Xp = X + (b * C_ + c) * HW_;
        const float* wp = dww + c * 9;
        float a = dwb[c];
#pragma unroll
        for (int dy = -1; dy <= 1; ++dy) {
          int hh = h + dy;
          if (hh < 0 || hh >= H_) continue;
          const float* row = Xp + hh * W_;
          const float* wr = wp + (dy + 1) * 3;
          if (wg > 0) a += wr[0] * row[wg - 1];
          a += wr[1] * row[wg];
          if (wg < W_ - 1) a += wr[2] * row[wg + 1];
        }
        v[e] = a;
      }
      rb[u] = pk2(v[0], v[1]);
    }
  } else if (SHIFT) {
#pragma unroll
    for (int u = 0; u < 16; ++u) {
      float v[2];
#pragma unroll
      for (int e = 0; e < 2; ++e) {
        int c = cg * 32 + 2 * u + e;
        int g = c >> 4;
        int hh = h, ww = wg;
        bool ok = true;
        if (g == 0)      { ww = wg + 1; ok = ww < W_; }
        else if (g == 1) { ww = wg - 1; ok = ww >= 0; }
        else if (g == 2) { hh = h + 1;  ok = hh < H_; }
        else if (g == 3) { hh = h - 1;  ok = hh >= 0; }
        v[e] = ok ? X[(b * C_ + c) * HW_ + hh * W_ + ww] : 0.f;
      }
      rb[u] = pk2(v[0], v[1]);
    }
  } else {
#pragma unroll
    for (int u = 0; u < 16; ++u) {
      int c = cg * 32 + 2 * u;
      float v0 = X[(b * C_ + c) * HW_ + h * W_ + wg];
      float v1 = X[(b * C_ + c + 1) * HW_ + h * W_ + wg];
      rb[u] = pk2(v0, v1);
    }
  }
  int sw = px & 7;
#pragma unroll
  for (int q = 0; q < 4; ++q) {
    int clp = (cg * 4 + q) ^ sw;
    *(uint4*)&Xs[px * 64 + clp * 4] =
        make_uint4(rb[4 * q], rb[4 * q + 1], rb[4 * q + 2], rb[4 * q + 3]);
  }
  __syncthreads();

  // -------- K loop: 8 steps x 2 p-tiles --------
  f32x16 acc0 = {}, acc1 = {};
  int xsw = lr & 7;
#pragma unroll
  for (int kk = 0; kk < 8; ++kk) {
    int cl = 2 * kk + hi;
    bf16x8 x0 = *(const bf16x8*)&Xs[lr * 64 + (cl ^ xsw) * 4];
    bf16x8 x1 = *(const bf16x8*)&Xs[(32 + lr) * 64 + (cl ^ xsw) * 4];
    acc0 = __builtin_amdgcn_mfma_f32_32x32x16_bf16(wf[kk], x0, acc0, 0, 0, 0);
    acc1 = __builtin_amdgcn_mfma_f32_32x32x16_bf16(wf[kk], x1, acc1, 0, 0, 0);
  }

  // -------- epilogue: lane's rows o = wid*32 + (r&3)+8*(r>>2)+4*hi, col p --------
  int obase = wid * 32 + 4 * hi;
  if (TRANS) {
#pragma unroll
    for (int r = 0; r < 16; ++r) {
      float bb = cb[obase + (r & 3) + 8 * (r >> 2)];
      acc0[r] += bb; acc1[r] += bb;
    }
  }
  if (RESID) {
#pragma unroll
    for (int r = 0; r < 16; ++r) {
      int o = obase + (r & 3) + 8 * (r >> 2);
      const float* rp = R + (b * C_ + o) * HW_ + h * W_ + w0;
      acc0[r] += rp[lr];
      acc1[r] += rp[32 + lr];
    }
  }
  if (LN) {
    float s0 = 0, s1 = 0, q0 = 0, q1 = 0;
#pragma unroll
    for (int r = 0; r < 16; ++r) {
      s0 += acc0[r]; q0 += acc0[r] * acc0[r];
      s1 += acc1[r]; q1 += acc1[r] * acc1[r];
    }
    s0 += __shfl_xor(s0, 32); q0 += __shfl_xor(q0, 32);
    s1 += __shfl_xor(s1, 32); q1 += __shfl_xor(q1, 32);
    if (hi == 0) {
      red[wid * 64 + lr] = s0;       red[wid * 64 + 32 + lr] = s1;
      red[256 + wid * 64 + lr] = q0; red[256 + wid * 64 + 32 + lr] = q1;
    }
    __syncthreads();
    if (t < 64) {
      float ss = red[t] + red[64 + t] + red[128 + t] + red[192 + t];
      float qq = red[256 + t] + red[320 + t] + red[384 + t] + red[448 + t];
      float mu = ss * (1.0f / 128.0f);
      float var = qq * (1.0f / 128.0f) - mu * mu;   // biased
      red[512 + t] = mu;
      red[576 + t] = rsqrtf(var + 1e-6f);
    }
    __syncthreads();
    float mu0 = red[512 + lr], rs0 = red[576 + lr];
    float mu1 = red[544 + lr], rs1 = red[608 + lr];
#pragma unroll
    for (int r = 0; r < 16; ++r) {
      int o = obase + (r & 3) + 8 * (r >> 2);
      float lw = lnw[o], lb2 = lnb[o];
      acc0[r] = lw * ((acc0[r] - mu0) * rs0) + lb2;
      acc1[r] = lw * ((acc1[r] - mu1) * rs1) + lb2;
    }
  }
#pragma unroll
  for (int r = 0; r < 16; ++r) {
    int o = obase + (r & 3) + 8 * (r >> 2);
    float* op = O + (b * C_ + o) * HW_ + h * W_ + w0;
    op[lr] = acc0[r];
    op[32 + lr] = acc1[r];
  }
}

// ============ MFMA attention (unchanged from verified round 2) ============
DEVI bf16x8 ldfrag(const unsigned* A, int r, int cl) {
  int clp = cl ^ ((r >> 1) & 3);
  uint4 v = *(const uint4*)(A + r * 16 + clp * 4);
  return __builtin_bit_cast(bf16x8, v);
}

DEVI bf16x8 vfrag(const unsigned* Vt, int c, int ktg, int hi) {
  int jc = 2 * ktg + hi;
  int jcp = jc ^ (c & 7);
  uint4 v = *(const uint4*)(Vt + c * 128 + jcp * 4);
  return __builtin_bit_cast(bf16x8, v);
}

DEVI void stageQ(const float* __restrict__ G, unsigned* A, int t) {
  unsigned row[16];
#pragma unroll
  for (int c = 0; c < 16; ++c)
    row[c] = pk2(G[(2 * c) * HW_ + t], G[(2 * c + 1) * HW_ + t]);
  int sw = (t >> 1) & 3;
#pragma unroll
  for (int cl = 0; cl < 4; ++cl) {
    int clp = cl ^ sw;
    *(uint4*)(A + t * 16 + clp * 4) =
        make_uint4(row[cl * 4], row[cl * 4 + 1], row[cl * 4 + 2], row[cl * 4 + 3]);
  }
}

DEVI void stageV(const float* __restrict__ G, unsigned* Vt, float* psv, int t) {
  int c = t >> 3, jb = t & 7;
  const float* src = G + c * HW_ + jb * 32;
  float sum = 0.f;
#pragma unroll
  for (int qd = 0; qd < 4; ++qd) {
    float4 a = *(const float4*)(src + qd * 8);
    float4 bq = *(const float4*)(src + qd * 8 + 4);
    sum += a.x + a.y + a.z + a.w + bq.x + bq.y + bq.z + bq.w;
    int jc = jb * 4 + qd;
    int jcp = jc ^ (c & 7);
    *(uint4*)(Vt + c * 128 + jcp * 4) =
        make_uint4(pk2(a.x, a.y), pk2(a.z, a.w), pk2(bq.x, bq.y), pk2(bq.z, bq.w));
  }
  psv[jb * 32 + c] = sum;
}

template <int DIR>
DEVI void attn_pass(const unsigned* Ql_, const unsigned* Qk_, const unsigned* Vt,
                    const float* psv, float* emr, float* __restrict__ outG,
                    int wid, int lane) {
  int hi = lane >> 5, cq = lane & 31;
#pragma unroll
  for (int s = 0; s < 2; ++s) {
    int qt = 2 * wid + s;
    int q = qt * 32 + cq;
    int jt0 = DIR ? qt : (qt >= 3 ? qt - 3 : 0);
    int jt1 = DIR ? (qt <= 4 ? qt + 3 : 7) : qt;
    int nt = jt1 - jt0 + 1;                      // wave-uniform (1..4)
    bf16x8 bq0 = ldfrag(Ql_, q, hi);
    bf16x8 bq1 = ldfrag(Ql_, q, hi + 2);
    f32x16 S[4];
#pragma unroll
    for (int ji = 0; ji < 4; ++ji) {
      if (ji < nt) {
        int jt = jt0 + ji;
        f32x16 d = {};
        d = __builtin_amdgcn_mfma_f32_32x32x16_bf16(
            ldfrag(Qk_, jt * 32 + cq, hi), bq0, d, 0, 0, 0);
        d = __builtin_amdgcn_mfma_f32_32x32x16_bf16(
            ldfrag(Qk_, jt * 32 + cq, hi + 2), bq1, d, 0, 0, 0);
        S[ji] = d;
      }
    }
    float m = 0.f;
#pragma unroll
    for (int ji = 0; ji < 4; ++ji) if (ji < nt) {
      int jb = (jt0 + ji) * 32 + 4 * hi;
#pragma unroll
      for (int r = 0; r < 16; ++r) {
        int j = jb + (r & 3) + 8 * (r >> 2);
        bool act = DIR ? (j >= q && j <= q + MD_) : (j <= q && j >= q - MD_);
        float v = act ? S[ji][r] : 0.f;
        S[ji][r] = v;
        m = fmaxf(m, v);
      }
    }
    m = fmaxf(m, __shfl_xor(m, 32));
    float em_ = __expf(-m);
    float lsum = 0.f;
#pragma unroll
    for (int ji = 0; ji < 4; ++ji) if (ji < nt) {
#pragma unroll
      for (int r = 0; r < 16; ++r) {
        float e = __expf(S[ji][r] - m);
        S[ji][r] = e;
        lsum += e;
      }
    }
    lsum += __shfl_xor(lsum, 32);
    lsum += (float)((8 - nt) * 32) * em_;
    float rl = 1.f / lsum;
    if (hi == 0) { emr[qt * 32 + cq] = em_; emr[256 + qt * 32 + cq] = rl; }
    f32x16 acc = {};
#pragma unroll
    for (int ji = 0; ji < 4; ++ji) if (ji < nt) {
      int jt = jt0 + ji;
      unsigned x[8], ox[8];
#pragma unroll
      for (int w2 = 0; w2 < 8; ++w2) x[w2] = pk2(S[ji][2 * w2], S[ji][2 * w2 + 1]);
#pragma unroll
      for (int w2 = 0; w2 < 8; ++w2) ox[w2] = __shfl_xor(x[w2], 32);
#pragma unroll
      for (int hf = 0; hf < 2; ++hf) {
        unsigned w0 = hi ? ox[4 * hf + 2] : x[4 * hf + 0];
        unsigned w1 = hi ? ox[4 * hf + 3] : x[4 * hf + 1];
        unsigned w2_ = hi ? x[4 * hf + 2] : ox[4 * hf + 0];
        unsigned w3 = hi ? x[4 * hf + 3] : ox[4 * hf + 1];
        uint4 aw = make_uint4(w0, w1, w2_, w3);
        acc = __builtin_amdgcn_mfma_f32_32x32x16_bf16(
            __builtin_bit_cast(bf16x8, aw), vfrag(Vt, cq, 2 * jt + hf, hi),
            acc, 0, 0, 0);
      }
    }
    float Rv = 0.f;
#pragma unroll
    for (int jt = 0; jt < 8; ++jt)
      if (jt < jt0 || jt > jt1) Rv += psv[jt * 32 + cq];
#pragma unroll
    for (int r = 0; r < 16; ++r) {
      int qr_ = (r & 3) + 8 * (r >> 2) + 4 * hi;
      float emq = emr[qt * 32 + qr_];
      float rlq = emr[256 + qt * 32 + qr_];
      outG[cq * HW_ + qt * 32 + qr_] = (acc[r] + emq * Rv) * rlq;
    }
  }
}

__global__ __launch_bounds__(256) void k_attn(
    const float* __restrict__ ql, const float* __restrict__ qr,
    const float* __restrict__ vl, const float* __restrict__ vr,
    float* __restrict__ outL, float* __restrict__ outR) {
  __shared__ __align__(16) unsigned Ql[4096];
  __shared__ __align__(16) unsigned Qr[4096];
  __shared__ __align__(16) unsigned Vt[4096];
  __shared__ float psv[256];
  __shared__ float emr[512];
  int t = threadIdx.x;
  int bid = blockIdx.x;                 // 1024 = B*NW*H
  int b = bid >> 9, k4 = (bid >> 7) & 3, h = bid & 127;
  int base = b * CHW_ + k4 * CG_ * HW_ + h * W_;
  stageQ(ql + base, Ql, t);
  stageQ(qr + base, Qr, t);
  stageV(vr + base, Vt, psv, t);
  __syncthreads();
  int wid = t >> 6, lane = t & 63;
  attn_pass<0>(Ql, Qr, Vt, psv, emr, outL + base, wid, lane);
  __syncthreads();
  stageV(vl + base, Vt, psv, t);
  __syncthreads();
  attn_pass<1>(Qr, Ql, Vt, psv, emr, outR + base, wid, lane);
}

// ---------------- launch ----------------
extern "C" void kernel_launch(void* const* d_in, const int* in_sizes, int n_in,
                              void* d_out, int out_size, void* d_ws, size_t ws_size,
                              hipStream_t stream) {
  const float* xl0    = (const float*)d_in[0];
  const float* xr0    = (const float*)d_in[1];
  const float* ln_l_w = (const float*)d_in[2];
  const float* ln_l_b = (const float*)d_in[3];
  const float* ln_r_w = (const float*)d_in[4];
  const float* ln_r_b = (const float*)d_in[5];
  const float* feaL_w = (const float*)d_in[6];
  const float* feaR_w = (const float*)d_in[7];
  const float* to_l_w = (const float*)d_in[8];
  const float* to_r_w = (const float*)d_in[9];
  const float* td_w   = (const float*)d_in[10];
  const float* td_b   = (const float*)d_in[11];
  const float* tp_w   = (const float*)d_in[12];
  const float* tp_b   = (const float*)d_in[13];
  const float* out_w  = (const float*)d_in[14];

  float* o0 = (float*)d_out;          // left (scratch: ql)
  float* o1 = o0 + TEN_;              // right (qr)
  float* ws = (float*)d_ws;
  float* b0 = ws;                     // x_left -> vl
  float* b1 = ws + TEN_;              // x_right -> vr
  unsigned short* wb = (unsigned short*)(ws + 2 * (size_t)TEN_);
  unsigned short* wb_feaL = wb + 0 * 16384;
  unsigned short* wb_feaR = wb + 1 * 16384;
  unsigned short* wb_tol  = wb + 2 * 16384;
  unsigned short* wb_tor  = wb + 3 * 16384;
  unsigned short* wb_tp   = wb + 4 * 16384;
  unsigned short* wb_out  = wb + 5 * 16384;

  WbPack pw;
  pw.s[0] = feaL_w; pw.s[1] = feaR_w; pw.s[2] = to_l_w;
  pw.s[3] = to_r_w; pw.s[4] = tp_w;   pw.s[5] = out_w;
  pw.d[0] = wb_feaL; pw.d[1] = wb_feaR; pw.d[2] = wb_tol;
  pw.d[3] = wb_tor;  pw.d[4] = wb_tp;   pw.d[5] = wb_out;
  k_wb<<<dim3(64, 6), 256, 0, stream>>>(pw);

  // transition (fused dw3x3) + tp_b + residual + LN -> x_left/x_right
  k_cmf<false, true, true, true><<<dim3(1024, 2), 256, 0, stream>>>(
      xl0, xr0, wb_tp, wb_tp, td_w, td_b, tp_b, xl0, xr0,
      ln_l_w, ln_l_b, ln_r_w, ln_r_b, b0, b1);

  // Q projections on shifted LN output -> d_out scratch
  k_cmf<true, false, false, false><<<dim3(1024, 2), 256, 0, stream>>>(
      b0, b1, wb_tol, wb_tor, nullptr, nullptr, nullptr, nullptr, nullptr,
      nullptr, nullptr, nullptr, nullptr, o0, o1);

  // V projections on shifted original inputs -> b0/b1 (x_left consumed)
  k_cmf<true, false, false, false><<<dim3(1024, 2), 256, 0, stream>>>(
      xl0, xr0, wb_feaL, wb_feaR, nullptr, nullptr, nullptr, nullptr, nullptr,
      nullptr, nullptr, nullptr, nullptr, b0, b1);

  // MFMA attention: warpL -> o0, warpR -> o1 (per-block in-place safe)
  k_attn<<<1024, 256, 0, stream>>>(o0, o1, b0, b1, o0, o1);

  // final conv + residual, in-place on d_out
  k_cmf<false, false, true, false><<<dim3(1024, 2), 256, 0, stream>>>(
      o0, o1, wb_out, wb_out, nullptr, nullptr, nullptr, xl0, xr0,
      nullptr, nullptr, nullptr, nullptr, o0, o1);
}

// Round 6
// 281.073 us; speedup vs baseline: 2.8600x; 1.3955x over previous
//
#include <hip/hip_runtime.h>

#define DEVI static __device__ __forceinline__

constexpr int B_ = 2, C_ = 128, H_ = 128, W_ = 256;
constexpr int CG_ = 32, MD_ = 96;
constexpr int HW_ = H_ * W_;        // 32768
constexpr int CHW_ = C_ * HW_;      // 4194304
constexpr int TEN_ = B_ * CHW_;     // 8388608 elements per tensor
constexpr int P16_ = TEN_ / 2;      // u32 count of a bf16-paired tensor

typedef short bf16x8 __attribute__((ext_vector_type(8)));
typedef float f32x16 __attribute__((ext_vector_type(16)));
typedef unsigned short ushort_t;

// ---------------- bf16 helpers ----------------
DEVI ushort_t f2b(float f) {
  unsigned u = __float_as_uint(f);
  return (ushort_t)((u + 0x7fffu + ((u >> 16) & 1u)) >> 16);   // RNE bf16
}
DEVI unsigned pk2(float a, float b) {
  return (unsigned)f2b(a) | ((unsigned)f2b(b) << 16);
}
DEVI float blo(unsigned u) { return __uint_as_float(u << 16); }
DEVI float bhi(unsigned u) { return __uint_as_float(u & 0xffff0000u); }
DEVI float sum8(uint4 v) {
  return blo(v.x) + bhi(v.x) + blo(v.y) + bhi(v.y) +
         blo(v.z) + bhi(v.z) + blo(v.w) + bhi(v.w);
}
DEVI int xcd_remap(int hw) { return (hw & 7) * 128 + (hw >> 3); }   // bijective, 1024%8==0

// ---------------- weight convert: Wb[o][k] bf16 ----------------
struct WbPack { const float* s[6]; ushort_t* d[6]; };

__global__ __launch_bounds__(256) void k_wb(WbPack p) {
  int m = blockIdx.y;
  int idx = blockIdx.x * 256 + threadIdx.x;
  p.d[m][idx] = f2b(p.s[m][idx]);
}

// ======== shared GEMM core (32x32x16 bf16, tile 64px x 128o) ========
// LDS Xs[px][64 u32 = 128ch bf16 pairs]; 16B cluster swizzle cl' = cl ^ (px&7).
DEVI void gemm_core(const unsigned* Xs, const ushort_t* Wb, int lane, int wid,
                    f32x16& acc0, f32x16& acc1) {
  int hi = lane >> 5, lr = lane & 31;
  bf16x8 wf[8];
  const ushort_t* wbase = Wb + (wid * 32 + lr) * 128 + hi * 8;
#pragma unroll
  for (int kk = 0; kk < 8; ++kk) wf[kk] = *(const bf16x8*)(wbase + kk * 16);
  int xsw = lr & 7;
#pragma unroll
  for (int kk = 0; kk < 8; ++kk) {
    int cl = 2 * kk + hi;
    bf16x8 x0 = *(const bf16x8*)&Xs[lr * 64 + ((cl ^ xsw) << 2)];
    bf16x8 x1 = *(const bf16x8*)&Xs[(32 + lr) * 64 + ((cl ^ xsw) << 2)];
    acc0 = __builtin_amdgcn_mfma_f32_32x32x16_bf16(wf[kk], x0, acc0, 0, 0, 0);
    acc1 = __builtin_amdgcn_mfma_f32_32x32x16_bf16(wf[kk], x1, acc1, 0, 0, 0);
  }
}

// ---------------- k_trans: dw3x3 + conv1x1 + bias + resid + LN -> bf16 pairs ----------------
// R3-form SCALAR staging (bisection: vectorized stencil reverted)
__global__ __launch_bounds__(256) void k_trans(
    const float* __restrict__ X0, const float* __restrict__ X1,
    const ushort_t* __restrict__ Wb,
    const float* __restrict__ dww, const float* __restrict__ dwb,
    const float* __restrict__ cb,
    const float* __restrict__ lnw0, const float* __restrict__ lnb0,
    const float* __restrict__ lnw1, const float* __restrict__ lnb1,
    unsigned* __restrict__ O0, unsigned* __restrict__ O1) {
  __shared__ __align__(16) unsigned Xs[64 * 64];
  __shared__ float red[640];
  int side = blockIdx.y;
  const float* X = side ? X1 : X0;
  const float* lnw = side ? lnw1 : lnw0;
  const float* lnb = side ? lnb1 : lnb0;
  unsigned* O = side ? O1 : O0;
  int bid = xcd_remap(blockIdx.x);
  int b = bid >> 9, h = (bid >> 2) & 127, w0 = (bid & 3) << 6;
  int t = threadIdx.x;
  int lane = t & 63, wid = t >> 6, hi = lane >> 5, lr = lane & 31;

  int px = t & 63, cg = t >> 6;
  int wg = w0 + px;
  unsigned rb[16];
#pragma unroll
  for (int u = 0; u < 16; ++u) {
    float v2[2];
#pragma unroll
    for (int e = 0; e < 2; ++e) {
      int c = cg * 32 + 2 * u + e;
      const float* Xp = X + (b * C_ + c) * HW_;
      const float* wp = dww + c * 9;
      float a = dwb[c];
#pragma unroll
      for (int dy = -1; dy <= 1; ++dy) {
        int hh = h + dy;
        if (hh < 0 || hh >= H_) continue;
        const float* row = Xp + hh * W_;
        const float* wr = wp + (dy + 1) * 3;
        if (wg > 0) a += wr[0] * row[wg - 1];
        a += wr[1] * row[wg];
        if (wg < W_ - 1) a += wr[2] * row[wg + 1];
      }
      v2[e] = a;
    }
    rb[u] = pk2(v2[0], v2[1]);
  }
  int sw = px & 7;
#pragma unroll
  for (int q2 = 0; q2 < 4; ++q2) {
    int clp = (cg * 4 + q2) ^ sw;
    *(uint4*)&Xs[px * 64 + clp * 4] =
        make_uint4(rb[4 * q2], rb[4 * q2 + 1], rb[4 * q2 + 2], rb[4 * q2 + 3]);
  }
  __syncthreads();

  f32x16 acc0 = {}, acc1 = {};
  gemm_core(Xs, Wb, lane, wid, acc0, acc1);

  int obase = wid * 32 + 4 * hi;
#pragma unroll
  for (int r = 0; r < 16; ++r) {
    int o = obase + (r & 3) + 8 * (r >> 2);
    float bb = cb[o];
    const float* rp = X + (b * C_ + o) * HW_ + h * W_ + w0;
    acc0[r] += bb + rp[lr];
    acc1[r] += bb + rp[32 + lr];
  }
  {
    float s0 = 0, s1 = 0, q0 = 0, q1 = 0;
#pragma unroll
    for (int r = 0; r < 16; ++r) {
      s0 += acc0[r]; q0 += acc0[r] * acc0[r];
      s1 += acc1[r]; q1 += acc1[r] * acc1[r];
    }
    s0 += __shfl_xor(s0, 32); q0 += __shfl_xor(q0, 32);
    s1 += __shfl_xor(s1, 32); q1 += __shfl_xor(q1, 32);
    if (hi == 0) {
      red[wid * 64 + lr] = s0;       red[wid * 64 + 32 + lr] = s1;
      red[256 + wid * 64 + lr] = q0; red[256 + wid * 64 + 32 + lr] = q1;
    }
    __syncthreads();
    if (t < 64) {
      float ss = red[t] + red[64 + t] + red[128 + t] + red[192 + t];
      float qq = red[256 + t] + red[320 + t] + red[384 + t] + red[448 + t];
      float mu = ss * (1.0f / 128.0f);
      float var = qq * (1.0f / 128.0f) - mu * mu;   // biased
      red[512 + t] = mu;
      red[576 + t] = rsqrtf(var + 1e-6f);
    }
    __syncthreads();
    float mu0 = red[512 + lr], rs0 = red[576 + lr];
    float mu1 = red[544 + lr], rs1 = red[608 + lr];
#pragma unroll
    for (int r = 0; r < 16; ++r) {
      int o = obase + (r & 3) + 8 * (r >> 2);
      float lw = lnw[o], lb2 = lnb[o];
      acc0[r] = lw * ((acc0[r] - mu0) * rs0) + lb2;
      acc1[r] = lw * ((acc1[r] - mu1) * rs1) + lb2;
    }
  }
  // bf16 channel-paired compact [b*64 + c2][HW]
#pragma unroll
  for (int r = 0; r < 16; r += 2) {
    int o = obase + (r & 3) + 8 * (r >> 2);
    unsigned* orow = O + (b * 64 + (o >> 1)) * HW_ + h * W_ + w0;
    orow[lr] = pk2(acc0[r], acc0[r + 1]);
    orow[32 + lr] = pk2(acc1[r], acc1[r + 1]);
  }
}

// ---------------- k_qv: Q (shifted x_left pairs) / V (shifted f32 input) ----------------
// R3-form SCALAR staging (bisection). Q out even-slot strided in d_out; V out compact ws.
__global__ __launch_bounds__(256) void k_qv(
    const unsigned* __restrict__ B0, const unsigned* __restrict__ B1,
    const float* __restrict__ X0, const float* __restrict__ X1,
    const ushort_t* __restrict__ WQ0, const ushort_t* __restrict__ WQ1,
    const ushort_t* __restrict__ WV0, const ushort_t* __restrict__ WV1,
    unsigned* __restrict__ Q0, unsigned* __restrict__ Q1,
    unsigned* __restrict__ V0, unsigned* __restrict__ V1) {
  __shared__ __align__(16) unsigned Xs[64 * 64];
  int ty = blockIdx.y;                // 0 QL, 1 QR, 2 VL, 3 VR
  int bid = xcd_remap(blockIdx.x);
  int b = bid >> 9, h = (bid >> 2) & 127, w0 = (bid & 3) << 6;
  int t = threadIdx.x;
  int lane = t & 63, wid = t >> 6, hi = lane >> 5, lr = lane & 31;
  const ushort_t* Wb = (ty == 0) ? WQ0 : (ty == 1) ? WQ1 : (ty == 2) ? WV0 : WV1;

  int px = t & 63, cg = t >> 6;
  int wg = w0 + px;
  unsigned rb[16];
  if (ty < 2) {
    const unsigned* S = ty ? B1 : B0;
#pragma unroll
    for (int u = 0; u < 16; ++u) {
      int c2 = cg * 16 + u;           // channel-pair 0..63
      int g = c2 >> 3;                // shift group (16-ch = 8-pair granules)
      int hh = h, ww = wg;
      bool ok = true;
      if (g == 0)      { ww = wg + 1; ok = ww < W_; }
      else if (g == 1) { ww = wg - 1; ok = ww >= 0; }
      else if (g == 2) { hh = h + 1;  ok = hh < H_; }
      else if (g == 3) { hh = h - 1;  ok = hh >= 0; }
      rb[u] = ok ? S[(b * 64 + c2) * HW_ + hh * W_ + ww] : 0u;
    }
  } else {
    const float* S = (ty == 2) ? X0 : X1;
#pragma unroll
    for (int u = 0; u < 16; ++u) {
      float v2[2];
#pragma unroll
      for (int e = 0; e < 2; ++e) {
        int c = cg * 32 + 2 * u + e;
        int g = c >> 4;
        int hh = h, ww = wg;
        bool ok = true;
        if (g == 0)      { ww = wg + 1; ok = ww < W_; }
        else if (g == 1) { ww = wg - 1; ok = ww >= 0; }
        else if (g == 2) { hh = h + 1;  ok = hh < H_; }
        else if (g == 3) { hh = h - 1;  ok = hh >= 0; }
        v2[e] = ok ? S[(b * C_ + c) * HW_ + hh * W_ + ww] : 0.f;
      }
      rb[u] = pk2(v2[0], v2[1]);
    }
  }
  int sw = px & 7;
#pragma unroll
  for (int q2 = 0; q2 < 4; ++q2) {
    int clp = (cg * 4 + q2) ^ sw;
    *(uint4*)&Xs[px * 64 + clp * 4] =
        make_uint4(rb[4 * q2], rb[4 * q2 + 1], rb[4 * q2 + 2], rb[4 * q2 + 3]);
  }
  __syncthreads();

  f32x16 acc0 = {}, acc1 = {};
  gemm_core(Xs, Wb, lane, wid, acc0, acc1);

  int obase = wid * 32 + 4 * hi;
  if (ty < 2) {
    unsigned* O = ty ? Q1 : Q0;
#pragma unroll
    for (int r = 0; r < 16; r += 2) {
      int o = obase + (r & 3) + 8 * (r >> 2);                 // even
      unsigned* orow = O + b * CHW_ + o * HW_ + h * W_ + w0;  // even-slot strided
      orow[lr] = pk2(acc0[r], acc0[r + 1]);
      orow[32 + lr] = pk2(acc1[r], acc1[r + 1]);
    }
  } else {
    unsigned* O = (ty == 2) ? V0 : V1;
#pragma unroll
    for (int r = 0; r < 16; r += 2) {
      int o = obase + (r & 3) + 8 * (r >> 2);                 // even
      unsigned* orow = O + (b * 64 + (o >> 1)) * HW_ + h * W_ + w0;
      orow[lr] = pk2(acc0[r], acc0[r + 1]);
      orow[32 + lr] = pk2(acc1[r], acc1[r + 1]);
    }
  }
}

// ============ MFMA attention ============
DEVI bf16x8 ldfrag(const unsigned* A, int r, int cl) {
  int clp = cl ^ ((r >> 1) & 3);
  uint4 v = *(const uint4*)(A + r * 16 + clp * 4);
  return __builtin_bit_cast(bf16x8, v);
}
DEVI bf16x8 vfrag(const unsigned* Vt, int c, int ktg, int hi) {
  int jc = 2 * ktg + hi;
  int jcp = jc ^ (c & 7);
  uint4 v = *(const uint4*)(Vt + c * 128 + jcp * 4);
  return __builtin_bit_cast(bf16x8, v);
}
// Q stage: even-slot strided pairs -> LDS [px][16 u32] swizzled
DEVI void stageQ16(const unsigned* __restrict__ G, unsigned* A, int t) {
  unsigned r[16];
#pragma unroll
  for (int c2 = 0; c2 < 16; ++c2) r[c2] = G[(2 * c2) * HW_ + t];
  int sw = (t >> 1) & 3;
#pragma unroll
  for (int cl = 0; cl < 4; ++cl) {
    int clp = cl ^ sw;
    *(uint4*)(A + t * 16 + clp * 4) =
        make_uint4(r[cl * 4], r[cl * 4 + 1], r[cl * 4 + 2], r[cl * 4 + 3]);
  }
}
// V stage: channel-paired global -> px-major Vt via b16 LDS transpose writes.
DEVI void stageVt(const unsigned* __restrict__ G, unsigned* Vt, int t) {
  ushort_t* V16 = (ushort_t*)Vt;
#pragma unroll
  for (int c2 = 0; c2 < 16; ++c2) {
    unsigned u = G[c2 * HW_ + t];
#pragma unroll
    for (int e = 0; e < 2; ++e) {
      int c = 2 * c2 + e;
      int w16 = (c * 128 + (((t >> 3) ^ (c & 7)) << 2) + ((t >> 1) & 3)) * 2 + (t & 1);
      V16[w16] = (ushort_t)(e ? (u >> 16) : (u & 0xffffu));
    }
  }
}
DEVI void psv_comp(const unsigned* Vt, float* psv, int t) {
  int jt = t >> 5, c = t & 31;
  float s = 0.f;
#pragma unroll
  for (int q = 0; q < 4; ++q) {
    int jcp = (4 * jt + q) ^ (c & 7);
    s += sum8(*(const uint4*)(Vt + c * 128 + jcp * 4));
  }
  psv[jt * 32 + c] = s;
}

template <int DIR>
DEVI void attn_pass(const unsigned* Ql_, const unsigned* Qk_, const unsigned* Vt,
                    const float* psv, float* emr, float* __restrict__ outG,
                    int wid, int lane) {
  int hi = lane >> 5, cq = lane & 31;
#pragma unroll
  for (int s = 0; s < 2; ++s) {
    int qt = 2 * wid + s;
    int q = qt * 32 + cq;
    int jt0 = DIR ? qt : (qt >= 3 ? qt - 3 : 0);
    int jt1 = DIR ? (qt <= 4 ? qt + 3 : 7) : qt;
    int nt = jt1 - jt0 + 1;                      // wave-uniform
    bf16x8 bq0 = ldfrag(Ql_, q, hi);
    bf16x8 bq1 = ldfrag(Ql_, q, hi + 2);
    f32x16 S[4];
#pragma unroll
    for (int ji = 0; ji < 4; ++ji) {
      if (ji < nt) {
        int jt = jt0 + ji;
        f32x16 d = {};
        d = __builtin_amdgcn_mfma_f32_32x32x16_bf16(
            ldfrag(Qk_, jt * 32 + cq, hi), bq0, d, 0, 0, 0);
        d = __builtin_amdgcn_mfma_f32_32x32x16_bf16(
            ldfrag(Qk_, jt * 32 + cq, hi + 2), bq1, d, 0, 0, 0);
        S[ji] = d;
      }
    }
    float m = 0.f;
#pragma unroll
    for (int ji = 0; ji < 4; ++ji) if (ji < nt) {
      int jb = (jt0 + ji) * 32 + 4 * hi;
#pragma unroll
      for (int r = 0; r < 16; ++r) {
        int j = jb + (r & 3) + 8 * (r >> 2);
        bool act = DIR ? (j >= q && j <= q + MD_) : (j <= q && j >= q - MD_);
        float v = act ? S[ji][r] : 0.f;
        S[ji][r] = v;
        m = fmaxf(m, v);
      }
    }
    m = fmaxf(m, __shfl_xor(m, 32));
    float em_ = __expf(-m);
    float lsum = 0.f;
#pragma unroll
    for (int ji = 0; ji < 4; ++ji) if (ji < nt) {
#pragma unroll
      for (int r = 0; r < 16; ++r) {
        float e = __expf(S[ji][r] - m);
        S[ji][r] = e;
        lsum += e;
      }
    }
    lsum += __shfl_xor(lsum, 32);
    lsum += (float)((8 - nt) * 32) * em_;
    float rl = 1.f / lsum;
    if (hi == 0) { emr[qt * 32 + cq] = em_; emr[256 + qt * 32 + cq] = rl; }
    f32x16 acc = {};
#pragma unroll
    for (int ji = 0; ji < 4; ++ji) if (ji < nt) {
      int jt = jt0 + ji;
      unsigned x[8], ox[8];
#pragma unroll
      for (int w2 = 0; w2 < 8; ++w2) x[w2] = pk2(S[ji][2 * w2], S[ji][2 * w2 + 1]);
#pragma unroll
      for (int w2 = 0; w2 < 8; ++w2) ox[w2] = __shfl_xor(x[w2], 32);
#pragma unroll
      for (int hf = 0; hf < 2; ++hf) {
        unsigned w0 = hi ? ox[4 * hf + 2] : x[4 * hf + 0];
        unsigned w1 = hi ? ox[4 * hf + 3] : x[4 * hf + 1];
        unsigned w2_ = hi ? x[4 * hf + 2] : ox[4 * hf + 0];
        unsigned w3 = hi ? x[4 * hf + 3] : ox[4 * hf + 1];
        uint4 aw = make_uint4(w0, w1, w2_, w3);
        acc = __builtin_amdgcn_mfma_f32_32x32x16_bf16(
            __builtin_bit_cast(bf16x8, aw), vfrag(Vt, cq, 2 * jt + hf, hi),
            acc, 0, 0, 0);
      }
    }
    float Rv = 0.f;
#pragma unroll
    for (int jt = 0; jt < 8; ++jt)
      if (jt < jt0 || jt > jt1) Rv += psv[jt * 32 + cq];
#pragma unroll
    for (int r = 0; r < 16; ++r) {
      int qr_ = (r & 3) + 8 * (r >> 2) + 4 * hi;
      float emq = emr[qt * 32 + qr_];
      float rlq = emr[256 + qt * 32 + qr_];
      outG[cq * HW_ + qt * 32 + qr_] = (acc[r] + emq * Rv) * rlq;   // f32 scatter
    }
  }
}

__global__ __launch_bounds__(256) void k_attn(
    const unsigned* __restrict__ qL, const unsigned* __restrict__ qR,
    const unsigned* __restrict__ vL, const unsigned* __restrict__ vR,
    float* __restrict__ wL, float* __restrict__ wR) {
  __shared__ __align__(16) unsigned Ql[4096];
  __shared__ __align__(16) unsigned Qr[4096];
  __shared__ __align__(16) unsigned Vt[4096];
  __shared__ float psv[256];
  __shared__ float emr[512];
  int t = threadIdx.x;
  int bid = blockIdx.x;
  int b = bid >> 9, k4 = (bid >> 7) & 3, h = bid & 127;
  int qoff = b * CHW_ + (k4 * CG_) * HW_ + h * W_;     // even-slot strided base
  int voff = (b * 64 + k4 * 16) * HW_ + h * W_;        // compact pair base
  stageQ16(qL + qoff, Ql, t);
  stageQ16(qR + qoff, Qr, t);
  stageVt(vR + voff, Vt, t);
  __syncthreads();
  psv_comp(Vt, psv, t);
  __syncthreads();
  int wid = t >> 6, lane = t & 63;
  attn_pass<0>(Ql, Qr, Vt, psv, emr, wL + qoff, wid, lane);
  __syncthreads();
  stageVt(vL + voff, Vt, t);
  __syncthreads();
  psv_comp(Vt, psv, t);
  __syncthreads();
  attn_pass<1>(Qr, Ql, Vt, psv, emr, wR + qoff, wid, lane);
}

// ---------------- k_fin: final conv + residual, in-place over f32 warp ----------------
__global__ __launch_bounds__(256) void k_fin(
    const float* __restrict__ Wf0, const float* __restrict__ Wf1,
    const float* __restrict__ X0, const float* __restrict__ X1,
    const ushort_t* __restrict__ Wb,
    float* __restrict__ O0, float* __restrict__ O1) {
  __shared__ __align__(16) unsigned Xs[64 * 64];
  int side = blockIdx.y;
  const float* Wf = side ? Wf1 : Wf0;
  const float* R = side ? X1 : X0;
  float* O = side ? O1 : O0;
  int bid = blockIdx.x;
  int b = bid >> 9, h = (bid >> 2) & 127, w0 = (bid & 3) << 6;
  int t = threadIdx.x;
  int lane = t & 63, wid = t >> 6, hi = lane >> 5, lr = lane & 31;
  int ch8 = t >> 4, pxq = t & 15;
  int c0 = ch8 * 8, wb2 = w0 + pxq * 4;
  float vv[8][4];
#pragma unroll
  for (int cc = 0; cc < 8; ++cc) {
    int c = c0 + cc;
    float4 a = *(const float4*)(Wf + (b * C_ + c) * HW_ + h * W_ + wb2);
    vv[cc][0] = a.x; vv[cc][1] = a.y; vv[cc][2] = a.z; vv[cc][3] = a.w;
  }
#pragma unroll
  for (int i = 0; i < 4; ++i) {
    int px = pxq * 4 + i;
    int cl = ch8 ^ (px & 7);
    *(uint4*)&Xs[px * 64 + cl * 4] =
        make_uint4(pk2(vv[0][i], vv[1][i]), pk2(vv[2][i], vv[3][i]),
                   pk2(vv[4][i], vv[5][i]), pk2(vv[6][i], vv[7][i]));
  }
  __syncthreads();
  f32x16 acc0 = {}, acc1 = {};
  gemm_core(Xs, Wb, lane, wid, acc0, acc1);
  int obase = wid * 32 + 4 * hi;
#pragma unroll
  for (int r = 0; r < 16; ++r) {
    int o = obase + (r & 3) + 8 * (r >> 2);
    const float* rp = R + (b * C_ + o) * HW_ + h * W_ + w0;
    float* op = O + (b * C_ + o) * HW_ + h * W_ + w0;
    op[lr] = acc0[r] + rp[lr];
    op[32 + lr] = acc1[r] + rp[32 + lr];
  }
}

// ---------------- launch ----------------
extern "C" void kernel_launch(void* const* d_in, const int* in_sizes, int n_in,
                              void* d_out, int out_size, void* d_ws, size_t ws_size,
                              hipStream_t stream) {
  const float* xl0    = (const float*)d_in[0];
  const float* xr0    = (const float*)d_in[1];
  const float* ln_l_w = (const float*)d_in[2];
  const float* ln_l_b = (const float*)d_in[3];
  const float* ln_r_w = (const float*)d_in[4];
  const float* ln_r_b = (const float*)d_in[5];
  const float* feaL_w = (const float*)d_in[6];
  const float* feaR_w = (const float*)d_in[7];
  const float* to_l_w = (const float*)d_in[8];
  const float* to_r_w = (const float*)d_in[9];
  const float* td_w   = (const float*)d_in[10];
  const float* td_b   = (const float*)d_in[11];
  const float* tp_w   = (const float*)d_in[12];
  const float* tp_b   = (const float*)d_in[13];
  const float* out_w  = (const float*)d_in[14];

  float* o0 = (float*)d_out;                 // final left; warpL lives here too
  float* o1 = o0 + TEN_;                     // final right; warpR
  unsigned* qL = (unsigned*)d_out;           // even-slot strided pairs in o0 region
  unsigned* qR = qL + TEN_;                  // in o1 region
  unsigned* bL = (unsigned*)d_ws;            // x_left bf16 pairs (compact)
  unsigned* bR = bL + P16_;
  unsigned* vL = bR + P16_;                  // V bf16 pairs (compact)
  unsigned* vR = vL + P16_;
  ushort_t* wb = (ushort_t*)(vR + P16_);
  ushort_t* wb_feaL = wb + 0 * 16384;
  ushort_t* wb_feaR = wb + 1 * 16384;
  ushort_t* wb_tol  = wb + 2 * 16384;
  ushort_t* wb_tor  = wb + 3 * 16384;
  ushort_t* wb_tp   = wb + 4 * 16384;
  ushort_t* wb_out  = wb + 5 * 16384;

  WbPack pw;
  pw.s[0] = feaL_w; pw.s[1] = feaR_w; pw.s[2] = to_l_w;
  pw.s[3] = to_r_w; pw.s[4] = tp_w;   pw.s[5] = out_w;
  pw.d[0] = wb_feaL; pw.d[1] = wb_feaR; pw.d[2] = wb_tol;
  pw.d[3] = wb_tor;  pw.d[4] = wb_tp;   pw.d[5] = wb_out;
  k_wb<<<dim3(64, 6), 256, 0, stream>>>(pw);

  // transition (fused dw3x3, scalar staging) + bias + resid + LN -> bf16 x_left/x_right
  k_trans<<<dim3(1024, 2), 256, 0, stream>>>(
      xl0, xr0, wb_tp, td_w, td_b, tp_b,
      ln_l_w, ln_l_b, ln_r_w, ln_r_b, bL, bR);

  // Q (shifted x_left/right) and V (shifted inputs) in one dispatch (scalar staging)
  k_qv<<<dim3(1024, 4), 256, 0, stream>>>(
      bL, bR, xl0, xr0, wb_tol, wb_tor, wb_feaL, wb_feaR,
      qL, qR, vL, vR);

  // MFMA attention -> f32 warp (in-place over Q regions; per-block safe)
  k_attn<<<1024, 256, 0, stream>>>(qL, qR, vL, vR, o0, o1);

  // final conv + residual, in-place over warp
  k_fin<<<dim3(1024, 2), 256, 0, stream>>>(
      o0, o1, xl0, xr0, wb_out, o0, o1);
}

// Round 8
// 202.007 us; speedup vs baseline: 3.9794x; 1.3914x over previous
//
#include <hip/hip_runtime.h>

#define DEVI static __device__ __forceinline__

constexpr int B_ = 2, C_ = 128, H_ = 128, W_ = 256;
constexpr int CG_ = 32, MD_ = 96;
constexpr int HW_ = H_ * W_;        // 32768
constexpr int CHW_ = C_ * HW_;      // 4194304
constexpr int TEN_ = B_ * CHW_;     // 8388608 elements per tensor
constexpr int P16_ = TEN_ / 2;      // u32 count of a bf16-paired tensor

typedef short bf16x8 __attribute__((ext_vector_type(8)));
typedef float f32x16 __attribute__((ext_vector_type(16)));
typedef unsigned short ushort_t;

// ---------------- bf16 helpers ----------------
DEVI ushort_t f2b(float f) {
  unsigned u = __float_as_uint(f);
  return (ushort_t)((u + 0x7fffu + ((u >> 16) & 1u)) >> 16);   // RNE bf16
}
DEVI unsigned pk2(float a, float b) {
  return (unsigned)f2b(a) | ((unsigned)f2b(b) << 16);
}
DEVI float blo(unsigned u) { return __uint_as_float(u << 16); }
DEVI float bhi(unsigned u) { return __uint_as_float(u & 0xffff0000u); }
DEVI float sum8(uint4 v) {
  return blo(v.x) + bhi(v.x) + blo(v.y) + bhi(v.y) +
         blo(v.z) + bhi(v.z) + blo(v.w) + bhi(v.w);
}
DEVI int xcd_remap(int hw) { return (hw & 7) * 128 + (hw >> 3); }   // bijective, 1024%8==0

// ---------------- weight convert: Wb[o][k] bf16 ----------------
struct WbPack { const float* s[6]; ushort_t* d[6]; };

__global__ __launch_bounds__(256) void k_wb(WbPack p) {
  int m = blockIdx.y;
  int idx = blockIdx.x * 256 + threadIdx.x;
  p.d[m][idx] = f2b(p.s[m][idx]);
}

// ======== shared GEMM core (32x32x16 bf16, tile 64px x 128o) ========
// LDS Xs[px][64 u32 = 128ch bf16 pairs]; 16B cluster swizzle cl' = cl ^ (px&7).
DEVI void gemm_core(const unsigned* Xs, const ushort_t* Wb, int lane, int wid,
                    f32x16& acc0, f32x16& acc1) {
  int hi = lane >> 5, lr = lane & 31;
  bf16x8 wf[8];
  const ushort_t* wbase = Wb + (wid * 32 + lr) * 128 + hi * 8;
#pragma unroll
  for (int kk = 0; kk < 8; ++kk) wf[kk] = *(const bf16x8*)(wbase + kk * 16);
  int xsw = lr & 7;
#pragma unroll
  for (int kk = 0; kk < 8; ++kk) {
    int cl = 2 * kk + hi;
    bf16x8 x0 = *(const bf16x8*)&Xs[lr * 64 + ((cl ^ xsw) << 2)];
    bf16x8 x1 = *(const bf16x8*)&Xs[(32 + lr) * 64 + ((cl ^ xsw) << 2)];
    acc0 = __builtin_amdgcn_mfma_f32_32x32x16_bf16(wf[kk], x0, acc0, 0, 0, 0);
    acc1 = __builtin_amdgcn_mfma_f32_32x32x16_bf16(wf[kk], x1, acc1, 0, 0, 0);
  }
}

// ---------------- k_trans: dw3x3 + conv1x1 + bias + resid + LN -> bf16 pairs ----------------
// Staging: thread = 4 ch x 8 px, float4 loads, taps applied as SEQUENTIAL +=
// statements in R6's exact order (bit-identical FMA sequence; OOB adds w*0.0).
__global__ __launch_bounds__(256) void k_trans(
    const float* __restrict__ X0, const float* __restrict__ X1,
    const ushort_t* __restrict__ Wb,
    const float* __restrict__ dww, const float* __restrict__ dwb,
    const float* __restrict__ cb,
    const float* __restrict__ lnw0, const float* __restrict__ lnb0,
    const float* __restrict__ lnw1, const float* __restrict__ lnb1,
    unsigned* __restrict__ O0, unsigned* __restrict__ O1) {
  __shared__ __align__(16) unsigned Xs[64 * 64];
  __shared__ float red[640];
  int side = blockIdx.y;
  const float* X = side ? X1 : X0;
  const float* lnw = side ? lnw1 : lnw0;
  const float* lnb = side ? lnb1 : lnb0;
  unsigned* O = side ? O1 : O0;
  int bid = xcd_remap(blockIdx.x);
  int b = bid >> 9, h = (bid >> 2) & 127, w0 = (bid & 3) << 6;
  int t = threadIdx.x;
  int lane = t & 63, wid = t >> 6, hi = lane >> 5, lr = lane & 31;

  // ---- staging: thread = (cg = t>>3 -> channels 4cg..4cg+3, oct = t&7 -> px 8oct..8oct+7)
  int oct = t & 7, cg = t >> 3;
  int c0 = cg * 4;
  int wb2 = w0 + oct * 8;
  float accs[4][8];
#pragma unroll
  for (int cc = 0; cc < 4; ++cc) {
    int c = c0 + cc;
    const float* Xp = X + (b * C_ + c) * HW_;
    const float* wp = dww + c * 9;
    float bb = dwb[c];
#pragma unroll
    for (int i = 0; i < 8; ++i) accs[cc][i] = bb;
#pragma unroll
    for (int dy = -1; dy <= 1; ++dy) {
      int hh = h + dy;
      if (hh < 0 || hh >= H_) continue;
      const float* row = Xp + hh * W_;
      float4 a = *(const float4*)(row + wb2);
      float4 bq = *(const float4*)(row + wb2 + 4);
      float vm = (wb2 > 0) ? row[wb2 - 1] : 0.f;
      float vp = (wb2 + 8 < W_) ? row[wb2 + 8] : 0.f;
      float v10[10] = {vm, a.x, a.y, a.z, a.w, bq.x, bq.y, bq.z, bq.w, vp};
      const float* wr = wp + (dy + 1) * 3;
      float tw0 = wr[0], tw1 = wr[1], tw2 = wr[2];
#pragma unroll
      for (int i = 0; i < 8; ++i) {
        accs[cc][i] += tw0 * v10[i];       // separate statements -> sequential
        accs[cc][i] += tw1 * v10[i + 1];   // v_fmac, same association as R6
        accs[cc][i] += tw2 * v10[i + 2];
      }
    }
  }
  // write: channel-pair words 2cg,2cg+1 (cluster cg>>1, wic 2(cg&1)), swizzle ^pxl
#pragma unroll
  for (int k = 0; k < 8; ++k) {
    int pxl = (k + oct) & 7;
    int px = oct * 8 + pxl;
    int cluster = ((cg >> 1) ^ pxl) & 15;
    *(uint2*)&Xs[px * 64 + cluster * 4 + (cg & 1) * 2] =
        make_uint2(pk2(accs[0][pxl], accs[1][pxl]), pk2(accs[2][pxl], accs[3][pxl]));
  }
  __syncthreads();

  f32x16 acc0 = {}, acc1 = {};
  gemm_core(Xs, Wb, lane, wid, acc0, acc1);

  int obase = wid * 32 + 4 * hi;
#pragma unroll
  for (int r = 0; r < 16; ++r) {
    int o = obase + (r & 3) + 8 * (r >> 2);
    float bb = cb[o];
    const float* rp = X + (b * C_ + o) * HW_ + h * W_ + w0;
    acc0[r] += bb + rp[lr];
    acc1[r] += bb + rp[32 + lr];
  }
  {
    float s0 = 0, s1 = 0, q0 = 0, q1 = 0;
#pragma unroll
    for (int r = 0; r < 16; ++r) {
      s0 += acc0[r]; q0 += acc0[r] * acc0[r];
      s1 += acc1[r]; q1 += acc1[r] * acc1[r];
    }
    s0 += __shfl_xor(s0, 32); q0 += __shfl_xor(q0, 32);
    s1 += __shfl_xor(s1, 32); q1 += __shfl_xor(q1, 32);
    if (hi == 0) {
      red[wid * 64 + lr] = s0;       red[wid * 64 + 32 + lr] = s1;
      red[256 + wid * 64 + lr] = q0; red[256 + wid * 64 + 32 + lr] = q1;
    }
    __syncthreads();
    if (t < 64) {
      float ss = red[t] + red[64 + t] + red[128 + t] + red[192 + t];
      float qq = red[256 + t] + red[320 + t] + red[384 + t] + red[448 + t];
      float mu = ss * (1.0f / 128.0f);
      float var = qq * (1.0f / 128.0f) - mu * mu;   // biased
      red[512 + t] = mu;
      red[576 + t] = rsqrtf(var + 1e-6f);
    }
    __syncthreads();
    float mu0 = red[512 + lr], rs0 = red[576 + lr];
    float mu1 = red[544 + lr], rs1 = red[608 + lr];
#pragma unroll
    for (int r = 0; r < 16; ++r) {
      int o = obase + (r & 3) + 8 * (r >> 2);
      float lw = lnw[o], lb2 = lnb[o];
      acc0[r] = lw * ((acc0[r] - mu0) * rs0) + lb2;
      acc1[r] = lw * ((acc1[r] - mu1) * rs1) + lb2;
    }
  }
  // bf16 channel-paired compact [b*64 + c2][HW]
#pragma unroll
  for (int r = 0; r < 16; r += 2) {
    int o = obase + (r & 3) + 8 * (r >> 2);
    unsigned* orow = O + (b * 64 + (o >> 1)) * HW_ + h * W_ + w0;
    orow[lr] = pk2(acc0[r], acc0[r + 1]);
    orow[32 + lr] = pk2(acc1[r], acc1[r + 1]);
  }
}

// ---------------- k_qv: UNCHANGED from R6 (scalar staging, verified) ----------------
__global__ __launch_bounds__(256) void k_qv(
    const unsigned* __restrict__ B0, const unsigned* __restrict__ B1,
    const float* __restrict__ X0, const float* __restrict__ X1,
    const ushort_t* __restrict__ WQ0, const ushort_t* __restrict__ WQ1,
    const ushort_t* __restrict__ WV0, const ushort_t* __restrict__ WV1,
    unsigned* __restrict__ Q0, unsigned* __restrict__ Q1,
    unsigned* __restrict__ V0, unsigned* __restrict__ V1) {
  __shared__ __align__(16) unsigned Xs[64 * 64];
  int ty = blockIdx.y;                // 0 QL, 1 QR, 2 VL, 3 VR
  int bid = xcd_remap(blockIdx.x);
  int b = bid >> 9, h = (bid >> 2) & 127, w0 = (bid & 3) << 6;
  int t = threadIdx.x;
  int lane = t & 63, wid = t >> 6, hi = lane >> 5, lr = lane & 31;
  const ushort_t* Wb = (ty == 0) ? WQ0 : (ty == 1) ? WQ1 : (ty == 2) ? WV0 : WV1;

  int px = t & 63, cg = t >> 6;
  int wg = w0 + px;
  unsigned rb[16];
  if (ty < 2) {
    const unsigned* S = ty ? B1 : B0;
#pragma unroll
    for (int u = 0; u < 16; ++u) {
      int c2 = cg * 16 + u;           // channel-pair 0..63
      int g = c2 >> 3;                // shift group (16-ch = 8-pair granules)
      int hh = h, ww = wg;
      bool ok = true;
      if (g == 0)      { ww = wg + 1; ok = ww < W_; }
      else if (g == 1) { ww = wg - 1; ok = ww >= 0; }
      else if (g == 2) { hh = h + 1;  ok = hh < H_; }
      else if (g == 3) { hh = h - 1;  ok = hh >= 0; }
      rb[u] = ok ? S[(b * 64 + c2) * HW_ + hh * W_ + ww] : 0u;
    }
  } else {
    const float* S = (ty == 2) ? X0 : X1;
#pragma unroll
    for (int u = 0; u < 16; ++u) {
      float v2[2];
#pragma unroll
      for (int e = 0; e < 2; ++e) {
        int c = cg * 32 + 2 * u + e;
        int g = c >> 4;
        int hh = h, ww = wg;
        bool ok = true;
        if (g == 0)      { ww = wg + 1; ok = ww < W_; }
        else if (g == 1) { ww = wg - 1; ok = ww >= 0; }
        else if (g == 2) { hh = h + 1;  ok = hh < H_; }
        else if (g == 3) { hh = h - 1;  ok = hh >= 0; }
        v2[e] = ok ? S[(b * C_ + c) * HW_ + hh * W_ + ww] : 0.f;
      }
      rb[u] = pk2(v2[0], v2[1]);
    }
  }
  int sw = px & 7;
#pragma unroll
  for (int q2 = 0; q2 < 4; ++q2) {
    int clp = (cg * 4 + q2) ^ sw;
    *(uint4*)&Xs[px * 64 + clp * 4] =
        make_uint4(rb[4 * q2], rb[4 * q2 + 1], rb[4 * q2 + 2], rb[4 * q2 + 3]);
  }
  __syncthreads();

  f32x16 acc0 = {}, acc1 = {};
  gemm_core(Xs, Wb, lane, wid, acc0, acc1);

  int obase = wid * 32 + 4 * hi;
  if (ty < 2) {
    unsigned* O = ty ? Q1 : Q0;
#pragma unroll
    for (int r = 0; r < 16; r += 2) {
      int o = obase + (r & 3) + 8 * (r >> 2);                 // even
      unsigned* orow = O + b * CHW_ + o * HW_ + h * W_ + w0;  // even-slot strided
      orow[lr] = pk2(acc0[r], acc0[r + 1]);
      orow[32 + lr] = pk2(acc1[r], acc1[r + 1]);
    }
  } else {
    unsigned* O = (ty == 2) ? V0 : V1;
#pragma unroll
    for (int r = 0; r < 16; r += 2) {
      int o = obase + (r & 3) + 8 * (r >> 2);                 // even
      unsigned* orow = O + (b * 64 + (o >> 1)) * HW_ + h * W_ + w0;
      orow[lr] = pk2(acc0[r], acc0[r + 1]);
      orow[32 + lr] = pk2(acc1[r], acc1[r + 1]);
    }
  }
}

// ============ MFMA attention (UNCHANGED from R6) ============
DEVI bf16x8 ldfrag(const unsigned* A, int r, int cl) {
  int clp = cl ^ ((r >> 1) & 3);
  uint4 v = *(const uint4*)(A + r * 16 + clp * 4);
  return __builtin_bit_cast(bf16x8, v);
}
DEVI bf16x8 vfrag(const unsigned* Vt, int c, int ktg, int hi) {
  int jc = 2 * ktg + hi;
  int jcp = jc ^ (c & 7);
  uint4 v = *(const uint4*)(Vt + c * 128 + jcp * 4);
  return __builtin_bit_cast(bf16x8, v);
}
// Q stage: even-slot strided pairs -> LDS [px][16 u32] swizzled
DEVI void stageQ16(const unsigned* __restrict__ G, unsigned* A, int t) {
  unsigned r[16];
#pragma unroll
  for (int c2 = 0; c2 < 16; ++c2) r[c2] = G[(2 * c2) * HW_ + t];
  int sw = (t >> 1) & 3;
#pragma unroll
  for (int cl = 0; cl < 4; ++cl) {
    int clp = cl ^ sw;
    *(uint4*)(A + t * 16 + clp * 4) =
        make_uint4(r[cl * 4], r[cl * 4 + 1], r[cl * 4 + 2], r[cl * 4 + 3]);
  }
}
// V stage: channel-paired global -> px-major Vt via b16 LDS transpose writes.
DEVI void stageVt(const unsigned* __restrict__ G, unsigned* Vt, int t) {
  ushort_t* V16 = (ushort_t*)Vt;
#pragma unroll
  for (int c2 = 0; c2 < 16; ++c2) {
    unsigned u = G[c2 * HW_ + t];
#pragma unroll
    for (int e = 0; e < 2; ++e) {
      int c = 2 * c2 + e;
      int w16 = (c * 128 + (((t >> 3) ^ (c & 7)) << 2) + ((t >> 1) & 3)) * 2 + (t & 1);
      V16[w16] = (ushort_t)(e ? (u >> 16) : (u & 0xffffu));
    }
  }
}
DEVI void psv_comp(const unsigned* Vt, float* psv, int t) {
  int jt = t >> 5, c = t & 31;
  float s = 0.f;
#pragma unroll
  for (int q = 0; q < 4; ++q) {
    int jcp = (4 * jt + q) ^ (c & 7);
    s += sum8(*(const uint4*)(Vt + c * 128 + jcp * 4));
  }
  psv[jt * 32 + c] = s;
}

template <int DIR>
DEVI void attn_pass(const unsigned* Ql_, const unsigned* Qk_, const unsigned* Vt,
                    const float* psv, float* emr, float* __restrict__ outG,
                    int wid, int lane) {
  int hi = lane >> 5, cq = lane & 31;
#pragma unroll
  for (int s = 0; s < 2; ++s) {
    int qt = 2 * wid + s;
    int q = qt * 32 + cq;
    int jt0 = DIR ? qt : (qt >= 3 ? qt - 3 : 0);
    int jt1 = DIR ? (qt <= 4 ? qt + 3 : 7) : qt;
    int nt = jt1 - jt0 + 1;                      // wave-uniform
    bf16x8 bq0 = ldfrag(Ql_, q, hi);
    bf16x8 bq1 = ldfrag(Ql_, q, hi + 2);
    f32x16 S[4];
#pragma unroll
    for (int ji = 0; ji < 4; ++ji) {
      if (ji < nt) {
        int jt = jt0 + ji;
        f32x16 d = {};
        d = __builtin_amdgcn_mfma_f32_32x32x16_bf16(
            ldfrag(Qk_, jt * 32 + cq, hi), bq0, d, 0, 0, 0);
        d = __builtin_amdgcn_mfma_f32_32x32x16_bf16(
            ldfrag(Qk_, jt * 32 + cq, hi + 2), bq1, d, 0, 0, 0);
        S[ji] = d;
      }
    }
    float m = 0.f;
#pragma unroll
    for (int ji = 0; ji < 4; ++ji) if (ji < nt) {
      int jb = (jt0 + ji) * 32 + 4 * hi;
#pragma unroll
      for (int r = 0; r < 16; ++r) {
        int j = jb + (r & 3) + 8 * (r >> 2);
        bool act = DIR ? (j >= q && j <= q + MD_) : (j <= q && j >= q - MD_);
        float v = act ? S[ji][r] : 0.f;
        S[ji][r] = v;
        m = fmaxf(m, v);
      }
    }
    m = fmaxf(m, __shfl_xor(m, 32));
    float em_ = __expf(-m);
    float lsum = 0.f;
#pragma unroll
    for (int ji = 0; ji < 4; ++ji) if (ji < nt) {
#pragma unroll
      for (int r = 0; r < 16; ++r) {
        float e = __expf(S[ji][r] - m);
        S[ji][r] = e;
        lsum += e;
      }
    }
    lsum += __shfl_xor(lsum, 32);
    lsum += (float)((8 - nt) * 32) * em_;
    float rl = 1.f / lsum;
    if (hi == 0) { emr[qt * 32 + cq] = em_; emr[256 + qt * 32 + cq] = rl; }
    f32x16 acc = {};
#pragma unroll
    for (int ji = 0; ji < 4; ++ji) if (ji < nt) {
      int jt = jt0 + ji;
      unsigned x[8], ox[8];
#pragma unroll
      for (int w2 = 0; w2 < 8; ++w2) x[w2] = pk2(S[ji][2 * w2], S[ji][2 * w2 + 1]);
#pragma unroll
      for (int w2 = 0; w2 < 8; ++w2) ox[w2] = __shfl_xor(x[w2], 32);
#pragma unroll
      for (int hf = 0; hf < 2; ++hf) {
        unsigned w0 = hi ? ox[4 * hf + 2] : x[4 * hf + 0];
        unsigned w1 = hi ? ox[4 * hf + 3] : x[4 * hf + 1];
        unsigned w2_ = hi ? x[4 * hf + 2] : ox[4 * hf + 0];
        unsigned w3 = hi ? x[4 * hf + 3] : ox[4 * hf + 1];
        uint4 aw = make_uint4(w0, w1, w2_, w3);
        acc = __builtin_amdgcn_mfma_f32_32x32x16_bf16(
            __builtin_bit_cast(bf16x8, aw), vfrag(Vt, cq, 2 * jt + hf, hi),
            acc, 0, 0, 0);
      }
    }
    float Rv = 0.f;
#pragma unroll
    for (int jt = 0; jt < 8; ++jt)
      if (jt < jt0 || jt > jt1) Rv += psv[jt * 32 + cq];
#pragma unroll
    for (int r = 0; r < 16; ++r) {
      int qr_ = (r & 3) + 8 * (r >> 2) + 4 * hi;
      float emq = emr[qt * 32 + qr_];
      float rlq = emr[256 + qt * 32 + qr_];
      outG[cq * HW_ + qt * 32 + qr_] = (acc[r] + emq * Rv) * rlq;   // f32 scatter
    }
  }
}

__global__ __launch_bounds__(256) void k_attn(
    const unsigned* __restrict__ qL, const unsigned* __restrict__ qR,
    const unsigned* __restrict__ vL, const unsigned* __restrict__ vR,
    float* __restrict__ wL, float* __restrict__ wR) {
  __shared__ __align__(16) unsigned Ql[4096];
  __shared__ __align__(16) unsigned Qr[4096];
  __shared__ __align__(16) unsigned Vt[4096];
  __shared__ float psv[256];
  __shared__ float emr[512];
  int t = threadIdx.x;
  int bid = blockIdx.x;
  int b = bid >> 9, k4 = (bid >> 7) & 3, h = bid & 127;
  int qoff = b * CHW_ + (k4 * CG_) * HW_ + h * W_;     // even-slot strided base
  int voff = (b * 64 + k4 * 16) * HW_ + h * W_;        // compact pair base
  stageQ16(qL + qoff, Ql, t);
  stageQ16(qR + qoff, Qr, t);
  stageVt(vR + voff, Vt, t);
  __syncthreads();
  psv_comp(Vt, psv, t);
  __syncthreads();
  int wid = t >> 6, lane = t & 63;
  attn_pass<0>(Ql, Qr, Vt, psv, emr, wL + qoff, wid, lane);
  __syncthreads();
  stageVt(vL + voff, Vt, t);
  __syncthreads();
  psv_comp(Vt, psv, t);
  __syncthreads();
  attn_pass<1>(Qr, Ql, Vt, psv, emr, wR + qoff, wid, lane);
}

// ---------------- k_fin: final conv + residual, in-place over f32 warp ----------------
__global__ __launch_bounds__(256) void k_fin(
    const float* __restrict__ Wf0, const float* __restrict__ Wf1,
    const float* __restrict__ X0, const float* __restrict__ X1,
    const ushort_t* __restrict__ Wb,
    float* __restrict__ O0, float* __restrict__ O1) {
  __shared__ __align__(16) unsigned Xs[64 * 64];
  int side = blockIdx.y;
  const float* Wf = side ? Wf1 : Wf0;
  const float* R = side ? X1 : X0;
  float* O = side ? O1 : O0;
  int bid = blockIdx.x;
  int b = bid >> 9, h = (bid >> 2) & 127, w0 = (bid & 3) << 6;
  int t = threadIdx.x;
  int lane = t & 63, wid = t >> 6, hi = lane >> 5, lr = lane & 31;
  int ch8 = t >> 4, pxq = t & 15;
  int c0 = ch8 * 8, wb2 = w0 + pxq * 4;
  float vv[8][4];
#pragma unroll
  for (int cc = 0; cc < 8; ++cc) {
    int c = c0 + cc;
    float4 a = *(const float4*)(Wf + (b * C_ + c) * HW_ + h * W_ + wb2);
    vv[cc][0] = a.x; vv[cc][1] = a.y; vv[cc][2] = a.z; vv[cc][3] = a.w;
  }
#pragma unroll
  for (int i = 0; i < 4; ++i) {
    int px = pxq * 4 + i;
    int cl = ch8 ^ (px & 7);
    *(uint4*)&Xs[px * 64 + cl * 4] =
        make_uint4(pk2(vv[0][i], vv[1][i]), pk2(vv[2][i], vv[3][i]),
                   pk2(vv[4][i], vv[5][i]), pk2(vv[6][i], vv[7][i]));
  }
  __syncthreads();
  f32x16 acc0 = {}, acc1 = {};
  gemm_core(Xs, Wb, lane, wid, acc0, acc1);
  int obase = wid * 32 + 4 * hi;
#pragma unroll
  for (int r = 0; r < 16; ++r) {
    int o = obase + (r & 3) + 8 * (r >> 2);
    const float* rp = R + (b * C_ + o) * HW_ + h * W_ + w0;
    float* op = O + (b * C_ + o) * HW_ + h * W_ + w0;
    op[lr] = acc0[r] + rp[lr];
    op[32 + lr] = acc1[r] + rp[32 + lr];
  }
}

// ---------------- launch ----------------
extern "C" void kernel_launch(void* const* d_in, const int* in_sizes, int n_in,
                              void* d_out, int out_size, void* d_ws, size_t ws_size,
                              hipStream_t stream) {
  const float* xl0    = (const float*)d_in[0];
  const float* xr0    = (const float*)d_in[1];
  const float* ln_l_w = (const float*)d_in[2];
  const float* ln_l_b = (const float*)d_in[3];
  const float* ln_r_w = (const float*)d_in[4];
  const float* ln_r_b = (const float*)d_in[5];
  const float* feaL_w = (const float*)d_in[6];
  const float* feaR_w = (const float*)d_in[7];
  const float* to_l_w = (const float*)d_in[8];
  const float* to_r_w = (const float*)d_in[9];
  const float* td_w   = (const float*)d_in[10];
  const float* td_b   = (const float*)d_in[11];
  const float* tp_w   = (const float*)d_in[12];
  const float* tp_b   = (const float*)d_in[13];
  const float* out_w  = (const float*)d_in[14];

  float* o0 = (float*)d_out;                 // final left; warpL lives here too
  float* o1 = o0 + TEN_;                     // final right; warpR
  unsigned* qL = (unsigned*)d_out;           // even-slot strided pairs in o0 region
  unsigned* qR = qL + TEN_;                  // in o1 region
  unsigned* bL = (unsigned*)d_ws;            // x_left bf16 pairs (compact)
  unsigned* bR = bL + P16_;
  unsigned* vL = bR + P16_;                  // V bf16 pairs (compact)
  unsigned* vR = vL + P16_;
  ushort_t* wb = (ushort_t*)(vR + P16_);
  ushort_t* wb_feaL = wb + 0 * 16384;
  ushort_t* wb_feaR = wb + 1 * 16384;
  ushort_t* wb_tol  = wb + 2 * 16384;
  ushort_t* wb_tor  = wb + 3 * 16384;
  ushort_t* wb_tp   = wb + 4 * 16384;
  ushort_t* wb_out  = wb + 5 * 16384;

  WbPack pw;
  pw.s[0] = feaL_w; pw.s[1] = feaR_w; pw.s[2] = to_l_w;
  pw.s[3] = to_r_w; pw.s[4] = tp_w;   pw.s[5] = out_w;
  pw.d[0] = wb_feaL; pw.d[1] = wb_feaR; pw.d[2] = wb_tol;
  pw.d[3] = wb_tor;  pw.d[4] = wb_tp;   pw.d[5] = wb_out;
  k_wb<<<dim3(64, 6), 256, 0, stream>>>(pw);

  // transition (fused dw3x3, vectorized loads, R6 tap order) + bias + resid + LN
  k_trans<<<dim3(1024, 2), 256, 0, stream>>>(
      xl0, xr0, wb_tp, td_w, td_b, tp_b,
      ln_l_w, ln_l_b, ln_r_w, ln_r_b, bL, bR);

  // Q (shifted x_left/right) and V (shifted inputs) in one dispatch (scalar staging)
  k_qv<<<dim3(1024, 4), 256, 0, stream>>>(
      bL, bR, xl0, xr0, wb_tol, wb_tor, wb_feaL, wb_feaR,
      qL, qR, vL, vR);

  // MFMA attention -> f32 warp (in-place over Q regions; per-block safe)
  k_attn<<<1024, 256, 0, stream>>>(qL, qR, vL, vR, o0, o1);

  // final conv + residual, in-place over warp
  k_fin<<<dim3(1024, 2), 256, 0, stream>>>(
      o0, o1, xl0, xr0, wb_out, o0, o1);
}

// Round 9
// 189.911 us; speedup vs baseline: 4.2329x; 1.0637x over previous
//
#include <hip/hip_runtime.h>

#define DEVI static __device__ __forceinline__

constexpr int B_ = 2, C_ = 128, H_ = 128, W_ = 256;
constexpr int CG_ = 32, MD_ = 96;
constexpr int HW_ = H_ * W_;        // 32768
constexpr int CHW_ = C_ * HW_;      // 4194304
constexpr int TEN_ = B_ * CHW_;     // 8388608 elements per tensor
constexpr int P16_ = TEN_ / 2;      // u32 count of a bf16-paired tensor

typedef short bf16x8 __attribute__((ext_vector_type(8)));
typedef float f32x16 __attribute__((ext_vector_type(16)));
typedef unsigned short ushort_t;

// ---------------- bf16 helpers ----------------
DEVI ushort_t f2b(float f) {
  unsigned u = __float_as_uint(f);
  return (ushort_t)((u + 0x7fffu + ((u >> 16) & 1u)) >> 16);   // RNE bf16
}
DEVI unsigned pk2(float a, float b) {
  return (unsigned)f2b(a) | ((unsigned)f2b(b) << 16);
}
DEVI float blo(unsigned u) { return __uint_as_float(u << 16); }
DEVI float bhi(unsigned u) { return __uint_as_float(u & 0xffff0000u); }
DEVI float sum8(uint4 v) {
  return blo(v.x) + bhi(v.x) + blo(v.y) + bhi(v.y) +
         blo(v.z) + bhi(v.z) + blo(v.w) + bhi(v.w);
}
DEVI int xcd_remap(int hw) { return (hw & 7) * 128 + (hw >> 3); }   // bijective, 1024%8==0

// ---------------- weight convert: Wb[o][k] bf16 ----------------
struct WbPack { const float* s[6]; ushort_t* d[6]; };

__global__ __launch_bounds__(256) void k_wb(WbPack p) {
  int m = blockIdx.y;
  int idx = blockIdx.x * 256 + threadIdx.x;
  p.d[m][idx] = f2b(p.s[m][idx]);
}

// ======== shared GEMM core (32x32x16 bf16, tile 64px x 128o) ========
// LDS Xs[px][64 u32 = 128ch bf16 pairs]; 16B cluster swizzle cl' = cl ^ (px&7).
DEVI void gemm_core(const unsigned* Xs, const ushort_t* Wb, int lane, int wid,
                    f32x16& acc0, f32x16& acc1) {
  int hi = lane >> 5, lr = lane & 31;
  bf16x8 wf[8];
  const ushort_t* wbase = Wb + (wid * 32 + lr) * 128 + hi * 8;
#pragma unroll
  for (int kk = 0; kk < 8; ++kk) wf[kk] = *(const bf16x8*)(wbase + kk * 16);
  int xsw = lr & 7;
#pragma unroll
  for (int kk = 0; kk < 8; ++kk) {
    int cl = 2 * kk + hi;
    bf16x8 x0 = *(const bf16x8*)&Xs[lr * 64 + ((cl ^ xsw) << 2)];
    bf16x8 x1 = *(const bf16x8*)&Xs[(32 + lr) * 64 + ((cl ^ xsw) << 2)];
    acc0 = __builtin_amdgcn_mfma_f32_32x32x16_bf16(wf[kk], x0, acc0, 0, 0, 0);
    acc1 = __builtin_amdgcn_mfma_f32_32x32x16_bf16(wf[kk], x1, acc1, 0, 0, 0);
  }
}

// ---------------- k_trans: dw3x3 + conv1x1 + bias + resid + LN -> bf16 pairs ----------------
// Staging: two independent channel-pair passes (register reduction); per-element
// tap order identical to R8 (sequential += statements).
__global__ __launch_bounds__(256) void k_trans(
    const float* __restrict__ X0, const float* __restrict__ X1,
    const ushort_t* __restrict__ Wb,
    const float* __restrict__ dww, const float* __restrict__ dwb,
    const float* __restrict__ cb,
    const float* __restrict__ lnw0, const float* __restrict__ lnb0,
    const float* __restrict__ lnw1, const float* __restrict__ lnb1,
    unsigned* __restrict__ O0, unsigned* __restrict__ O1) {
  __shared__ __align__(16) unsigned Xs[64 * 64];
  __shared__ float red[640];
  int side = blockIdx.y;
  const float* X = side ? X1 : X0;
  const float* lnw = side ? lnw1 : lnw0;
  const float* lnb = side ? lnb1 : lnb0;
  unsigned* O = side ? O1 : O0;
  int bid = xcd_remap(blockIdx.x);
  int b = bid >> 9, h = (bid >> 2) & 127, w0 = (bid & 3) << 6;
  int t = threadIdx.x;
  int lane = t & 63, wid = t >> 6, hi = lane >> 5, lr = lane & 31;

  // ---- staging: thread = (cg = t>>3 -> channels 4cg..4cg+3, oct = t&7 -> px 8oct..+7)
  int oct = t & 7, cg = t >> 3;
  int wb2 = w0 + oct * 8;
#pragma unroll
  for (int p = 0; p < 2; ++p) {        // channel pair p: channels 4cg+2p, 4cg+2p+1
    float accs[2][8];
#pragma unroll
    for (int cc = 0; cc < 2; ++cc) {
      int c = cg * 4 + p * 2 + cc;
      const float* Xp = X + (b * C_ + c) * HW_;
      const float* wp = dww + c * 9;
      float bb = dwb[c];
#pragma unroll
      for (int i = 0; i < 8; ++i) accs[cc][i] = bb;
#pragma unroll
      for (int dy = -1; dy <= 1; ++dy) {
        int hh = h + dy;
        if (hh < 0 || hh >= H_) continue;
        const float* row = Xp + hh * W_;
        float4 a = *(const float4*)(row + wb2);
        float4 bq = *(const float4*)(row + wb2 + 4);
        float vm = (wb2 > 0) ? row[wb2 - 1] : 0.f;
        float vp = (wb2 + 8 < W_) ? row[wb2 + 8] : 0.f;
        float v10[10] = {vm, a.x, a.y, a.z, a.w, bq.x, bq.y, bq.z, bq.w, vp};
        const float* wr = wp + (dy + 1) * 3;
        float tw0 = wr[0], tw1 = wr[1], tw2 = wr[2];
#pragma unroll
        for (int i = 0; i < 8; ++i) {
          accs[cc][i] += tw0 * v10[i];       // sequential v_fmac, R8 order
          accs[cc][i] += tw1 * v10[i + 1];
          accs[cc][i] += tw2 * v10[i + 2];
        }
      }
    }
    // write channel-pair word c2 = 2cg+p (cluster cg>>1, wic = (2cg+p)&3), swz ^pxl
    int wic = (2 * cg + p) & 3;
    int clb = cg >> 1;
#pragma unroll
    for (int k = 0; k < 8; ++k) {
      int pxl = (k + oct) & 7;
      int px = oct * 8 + pxl;
      Xs[px * 64 + (((clb ^ pxl) & 15) << 2) + wic] = pk2(accs[0][pxl], accs[1][pxl]);
    }
  }
  __syncthreads();

  f32x16 acc0 = {}, acc1 = {};
  gemm_core(Xs, Wb, lane, wid, acc0, acc1);

  int obase = wid * 32 + 4 * hi;
#pragma unroll
  for (int r = 0; r < 16; ++r) {
    int o = obase + (r & 3) + 8 * (r >> 2);
    float bb = cb[o];
    const float* rp = X + (b * C_ + o) * HW_ + h * W_ + w0;
    acc0[r] += bb + rp[lr];
    acc1[r] += bb + rp[32 + lr];
  }
  {
    float s0 = 0, s1 = 0, q0 = 0, q1 = 0;
#pragma unroll
    for (int r = 0; r < 16; ++r) {
      s0 += acc0[r]; q0 += acc0[r] * acc0[r];
      s1 += acc1[r]; q1 += acc1[r] * acc1[r];
    }
    s0 += __shfl_xor(s0, 32); q0 += __shfl_xor(q0, 32);
    s1 += __shfl_xor(s1, 32); q1 += __shfl_xor(q1, 32);
    if (hi == 0) {
      red[wid * 64 + lr] = s0;       red[wid * 64 + 32 + lr] = s1;
      red[256 + wid * 64 + lr] = q0; red[256 + wid * 64 + 32 + lr] = q1;
    }
    __syncthreads();
    if (t < 64) {
      float ss = red[t] + red[64 + t] + red[128 + t] + red[192 + t];
      float qq = red[256 + t] + red[320 + t] + red[384 + t] + red[448 + t];
      float mu = ss * (1.0f / 128.0f);
      float var = qq * (1.0f / 128.0f) - mu * mu;   // biased
      red[512 + t] = mu;
      red[576 + t] = rsqrtf(var + 1e-6f);
    }
    __syncthreads();
    float mu0 = red[512 + lr], rs0 = red[576 + lr];
    float mu1 = red[544 + lr], rs1 = red[608 + lr];
#pragma unroll
    for (int r = 0; r < 16; ++r) {
      int o = obase + (r & 3) + 8 * (r >> 2);
      float lw = lnw[o], lb2 = lnb[o];
      acc0[r] = lw * ((acc0[r] - mu0) * rs0) + lb2;
      acc1[r] = lw * ((acc1[r] - mu1) * rs1) + lb2;
    }
  }
  // bf16 channel-paired compact [b*64 + c2][HW]
#pragma unroll
  for (int r = 0; r < 16; r += 2) {
    int o = obase + (r & 3) + 8 * (r >> 2);
    unsigned* orow = O + (b * 64 + (o >> 1)) * HW_ + h * W_ + w0;
    orow[lr] = pk2(acc0[r], acc0[r + 1]);
    orow[32 + lr] = pk2(acc1[r], acc1[r + 1]);
  }
}

// ---------------- k_qv: Q / V projections, VECTORIZED staging (pure movement) ----------------
__global__ __launch_bounds__(256) void k_qv(
    const unsigned* __restrict__ B0, const unsigned* __restrict__ B1,
    const float* __restrict__ X0, const float* __restrict__ X1,
    const ushort_t* __restrict__ WQ0, const ushort_t* __restrict__ WQ1,
    const ushort_t* __restrict__ WV0, const ushort_t* __restrict__ WV1,
    unsigned* __restrict__ Q0, unsigned* __restrict__ Q1,
    unsigned* __restrict__ V0, unsigned* __restrict__ V1) {
  __shared__ __align__(16) unsigned Xs[64 * 64];
  int ty = blockIdx.y;                // 0 QL, 1 QR, 2 VL, 3 VR
  int bid = xcd_remap(blockIdx.x);
  int b = bid >> 9, h = (bid >> 2) & 127, w0 = (bid & 3) << 6;
  int t = threadIdx.x;
  int lane = t & 63, wid = t >> 6, hi = lane >> 5, lr = lane & 31;
  const ushort_t* Wb = (ty == 0) ? WQ0 : (ty == 1) ? WQ1 : (ty == 2) ? WV0 : WV1;

  if (ty < 2) {
    // ---- Q staging from bf16 channel-paired, shifted (pure u32 movement) ----
    const unsigned* S = ty ? B1 : B0;
#pragma unroll
    for (int uu = 0; uu < 4; ++uu) {
      int unit = uu * 256 + t;
      int c2u = unit >> 4, pxq = unit & 15;
      int wb2 = w0 + pxq * 4;
      int g = c2u >> 3;
      unsigned v[4];
      const unsigned* rowp = S + (b * 64 + c2u) * HW_ + h * W_;
      if (g >= 4) {
        uint4 a = *(const uint4*)(rowp + wb2);
        v[0] = a.x; v[1] = a.y; v[2] = a.z; v[3] = a.w;
      } else if (g >= 2) {
        int hh = h + (g == 2 ? 1 : -1);
        if (hh >= 0 && hh < H_) {
          uint4 a = *(const uint4*)(S + (b * 64 + c2u) * HW_ + hh * W_ + wb2);
          v[0] = a.x; v[1] = a.y; v[2] = a.z; v[3] = a.w;
        } else { v[0] = v[1] = v[2] = v[3] = 0u; }
      } else {
        int d = (g == 0) ? 1 : -1;
#pragma unroll
        for (int i = 0; i < 4; ++i) {
          int ww = wb2 + i + d;
          v[i] = (ww >= 0 && ww < W_) ? rowp[ww] : 0u;
        }
      }
#pragma unroll
      for (int i = 0; i < 4; ++i) {
        int px = pxq * 4 + i;
        Xs[px * 64 + (((c2u >> 2) ^ (px & 7)) << 2) + (c2u & 3)] = v[i];
      }
    }
  } else {
    // ---- V staging from f32, shifted (float4 + shifted reconstruct; pure movement) ----
    const float* S = (ty == 2) ? X0 : X1;
    int ch8 = t >> 4, pxq = t & 15;
    int c0 = ch8 * 8, wb2 = w0 + pxq * 4;
    float vv[8][4];
#pragma unroll
    for (int cc = 0; cc < 8; ++cc) {
      int c = c0 + cc;
      int g = c >> 4;
      const float* rowp = S + (b * C_ + c) * HW_ + h * W_;
      if (g >= 4) {
        float4 a = *(const float4*)(rowp + wb2);
        vv[cc][0] = a.x; vv[cc][1] = a.y; vv[cc][2] = a.z; vv[cc][3] = a.w;
      } else if (g >= 2) {
        int hh = h + (g == 2 ? 1 : -1);
        if (hh >= 0 && hh < H_) {
          float4 a = *(const float4*)(S + (b * C_ + c) * HW_ + hh * W_ + wb2);
          vv[cc][0] = a.x; vv[cc][1] = a.y; vv[cc][2] = a.z; vv[cc][3] = a.w;
        } else { vv[cc][0] = vv[cc][1] = vv[cc][2] = vv[cc][3] = 0.f; }
      } else if (g == 0) {       // w+1 shift
        float4 a = *(const float4*)(rowp + wb2);
        float x4 = (wb2 + 4 < W_) ? rowp[wb2 + 4] : 0.f;
        vv[cc][0] = a.y; vv[cc][1] = a.z; vv[cc][2] = a.w; vv[cc][3] = x4;
      } else {                    // w-1 shift
        float4 a = *(const float4*)(rowp + wb2);
        float xm = (wb2 > 0) ? rowp[wb2 - 1] : 0.f;
        vv[cc][0] = xm; vv[cc][1] = a.x; vv[cc][2] = a.y; vv[cc][3] = a.z;
      }
    }
#pragma unroll
    for (int i = 0; i < 4; ++i) {
      int px = pxq * 4 + i;
      int cl = ch8 ^ (px & 7);
      *(uint4*)&Xs[px * 64 + cl * 4] =
          make_uint4(pk2(vv[0][i], vv[1][i]), pk2(vv[2][i], vv[3][i]),
                     pk2(vv[4][i], vv[5][i]), pk2(vv[6][i], vv[7][i]));
    }
  }
  __syncthreads();

  f32x16 acc0 = {}, acc1 = {};
  gemm_core(Xs, Wb, lane, wid, acc0, acc1);

  int obase = wid * 32 + 4 * hi;
  if (ty < 2) {
    unsigned* O = ty ? Q1 : Q0;
#pragma unroll
    for (int r = 0; r < 16; r += 2) {
      int o = obase + (r & 3) + 8 * (r >> 2);                 // even
      unsigned* orow = O + b * CHW_ + o * HW_ + h * W_ + w0;  // even-slot strided
      orow[lr] = pk2(acc0[r], acc0[r + 1]);
      orow[32 + lr] = pk2(acc1[r], acc1[r + 1]);
    }
  } else {
    unsigned* O = (ty == 2) ? V0 : V1;
#pragma unroll
    for (int r = 0; r < 16; r += 2) {
      int o = obase + (r & 3) + 8 * (r >> 2);                 // even
      unsigned* orow = O + (b * 64 + (o >> 1)) * HW_ + h * W_ + w0;
      orow[lr] = pk2(acc0[r], acc0[r + 1]);
      orow[32 + lr] = pk2(acc1[r], acc1[r + 1]);
    }
  }
}

// ============ MFMA attention (UNCHANGED from R6/R8) ============
DEVI bf16x8 ldfrag(const unsigned* A, int r, int cl) {
  int clp = cl ^ ((r >> 1) & 3);
  uint4 v = *(const uint4*)(A + r * 16 + clp * 4);
  return __builtin_bit_cast(bf16x8, v);
}
DEVI bf16x8 vfrag(const unsigned* Vt, int c, int ktg, int hi) {
  int jc = 2 * ktg + hi;
  int jcp = jc ^ (c & 7);
  uint4 v = *(const uint4*)(Vt + c * 128 + jcp * 4);
  return __builtin_bit_cast(bf16x8, v);
}
DEVI void stageQ16(const unsigned* __restrict__ G, unsigned* A, int t) {
  unsigned r[16];
#pragma unroll
  for (int c2 = 0; c2 < 16; ++c2) r[c2] = G[(2 * c2) * HW_ + t];
  int sw = (t >> 1) & 3;
#pragma unroll
  for (int cl = 0; cl < 4; ++cl) {
    int clp = cl ^ sw;
    *(uint4*)(A + t * 16 + clp * 4) =
        make_uint4(r[cl * 4], r[cl * 4 + 1], r[cl * 4 + 2], r[cl * 4 + 3]);
  }
}
DEVI void stageVt(const unsigned* __restrict__ G, unsigned* Vt, int t) {
  ushort_t* V16 = (ushort_t*)Vt;
#pragma unroll
  for (int c2 = 0; c2 < 16; ++c2) {
    unsigned u = G[c2 * HW_ + t];
#pragma unroll
    for (int e = 0; e < 2; ++e) {
      int c = 2 * c2 + e;
      int w16 = (c * 128 + (((t >> 3) ^ (c & 7)) << 2) + ((t >> 1) & 3)) * 2 + (t & 1);
      V16[w16] = (ushort_t)(e ? (u >> 16) : (u & 0xffffu));
    }
  }
}
DEVI void psv_comp(const unsigned* Vt, float* psv, int t) {
  int jt = t >> 5, c = t & 31;
  float s = 0.f;
#pragma unroll
  for (int q = 0; q < 4; ++q) {
    int jcp = (4 * jt + q) ^ (c & 7);
    s += sum8(*(const uint4*)(Vt + c * 128 + jcp * 4));
  }
  psv[jt * 32 + c] = s;
}

template <int DIR>
DEVI void attn_pass(const unsigned* Ql_, const unsigned* Qk_, const unsigned* Vt,
                    const float* psv, float* emr, float* __restrict__ outG,
                    int wid, int lane) {
  int hi = lane >> 5, cq = lane & 31;
#pragma unroll
  for (int s = 0; s < 2; ++s) {
    int qt = 2 * wid + s;
    int q = qt * 32 + cq;
    int jt0 = DIR ? qt : (qt >= 3 ? qt - 3 : 0);
    int jt1 = DIR ? (qt <= 4 ? qt + 3 : 7) : qt;
    int nt = jt1 - jt0 + 1;                      // wave-uniform
    bf16x8 bq0 = ldfrag(Ql_, q, hi);
    bf16x8 bq1 = ldfrag(Ql_, q, hi + 2);
    f32x16 S[4];
#pragma unroll
    for (int ji = 0; ji < 4; ++ji) {
      if (ji < nt) {
        int jt = jt0 + ji;
        f32x16 d = {};
        d = __builtin_amdgcn_mfma_f32_32x32x16_bf16(
            ldfrag(Qk_, jt * 32 + cq, hi), bq0, d, 0, 0, 0);
        d = __builtin_amdgcn_mfma_f32_32x32x16_bf16(
            ldfrag(Qk_, jt * 32 + cq, hi + 2), bq1, d, 0, 0, 0);
        S[ji] = d;
      }
    }
    float m = 0.f;
#pragma unroll
    for (int ji = 0; ji < 4; ++ji) if (ji < nt) {
      int jb = (jt0 + ji) * 32 + 4 * hi;
#pragma unroll
      for (int r = 0; r < 16; ++r) {
        int j = jb + (r & 3) + 8 * (r >> 2);
        bool act = DIR ? (j >= q && j <= q + MD_) : (j <= q && j >= q - MD_);
        float v = act ? S[ji][r] : 0.f;
        S[ji][r] = v;
        m = fmaxf(m, v);
      }
    }
    m = fmaxf(m, __shfl_xor(m, 32));
    float em_ = __expf(-m);
    float lsum = 0.f;
#pragma unroll
    for (int ji = 0; ji < 4; ++ji) if (ji < nt) {
#pragma unroll
      for (int r = 0; r < 16; ++r) {
        float e = __expf(S[ji][r] - m);
        S[ji][r] = e;
        lsum += e;
      }
    }
    lsum += __shfl_xor(lsum, 32);
    lsum += (float)((8 - nt) * 32) * em_;
    float rl = 1.f / lsum;
    if (hi == 0) { emr[qt * 32 + cq] = em_; emr[256 + qt * 32 + cq] = rl; }
    f32x16 acc = {};
#pragma unroll
    for (int ji = 0; ji < 4; ++ji) if (ji < nt) {
      int jt = jt0 + ji;
      unsigned x[8], ox[8];
#pragma unroll
      for (int w2 = 0; w2 < 8; ++w2) x[w2] = pk2(S[ji][2 * w2], S[ji][2 * w2 + 1]);
#pragma unroll
      for (int w2 = 0; w2 < 8; ++w2) ox[w2] = __shfl_xor(x[w2], 32);
#pragma unroll
      for (int hf = 0; hf < 2; ++hf) {
        unsigned w0 = hi ? ox[4 * hf + 2] : x[4 * hf + 0];
        unsigned w1 = hi ? ox[4 * hf + 3] : x[4 * hf + 1];
        unsigned w2_ = hi ? x[4 * hf + 2] : ox[4 * hf + 0];
        unsigned w3 = hi ? x[4 * hf + 3] : ox[4 * hf + 1];
        uint4 aw = make_uint4(w0, w1, w2_, w3);
        acc = __builtin_amdgcn_mfma_f32_32x32x16_bf16(
            __builtin_bit_cast(bf16x8, aw), vfrag(Vt, cq, 2 * jt + hf, hi),
            acc, 0, 0, 0);
      }
    }
    float Rv = 0.f;
#pragma unroll
    for (int jt = 0; jt < 8; ++jt)
      if (jt < jt0 || jt > jt1) Rv += psv[jt * 32 + cq];
#pragma unroll
    for (int r = 0; r < 16; ++r) {
      int qr_ = (r & 3) + 8 * (r >> 2) + 4 * hi;
      float emq = emr[qt * 32 + qr_];
      float rlq = emr[256 + qt * 32 + qr_];
      outG[cq * HW_ + qt * 32 + qr_] = (acc[r] + emq * Rv) * rlq;   // f32 scatter
    }
  }
}

__global__ __launch_bounds__(256) void k_attn(
    const unsigned* __restrict__ qL, const unsigned* __restrict__ qR,
    const unsigned* __restrict__ vL, const unsigned* __restrict__ vR,
    float* __restrict__ wL, float* __restrict__ wR) {
  __shared__ __align__(16) unsigned Ql[4096];
  __shared__ __align__(16) unsigned Qr[4096];
  __shared__ __align__(16) unsigned Vt[4096];
  __shared__ float psv[256];
  __shared__ float emr[512];
  int t = threadIdx.x;
  int bid = blockIdx.x;
  int b = bid >> 9, k4 = (bid >> 7) & 3, h = bid & 127;
  int qoff = b * CHW_ + (k4 * CG_) * HW_ + h * W_;     // even-slot strided base
  int voff = (b * 64 + k4 * 16) * HW_ + h * W_;        // compact pair base
  stageQ16(qL + qoff, Ql, t);
  stageQ16(qR + qoff, Qr, t);
  stageVt(vR + voff, Vt, t);
  __syncthreads();
  psv_comp(Vt, psv, t);
  __syncthreads();
  int wid = t >> 6, lane = t & 63;
  attn_pass<0>(Ql, Qr, Vt, psv, emr, wL + qoff, wid, lane);
  __syncthreads();
  stageVt(vL + voff, Vt, t);
  __syncthreads();
  psv_comp(Vt, psv, t);
  __syncthreads();
  attn_pass<1>(Qr, Ql, Vt, psv, emr, wR + qoff, wid, lane);
}

// ---------------- k_fin: final conv + residual, in-place over f32 warp ----------------
__global__ __launch_bounds__(256) void k_fin(
    const float* __restrict__ Wf0, const float* __restrict__ Wf1,
    const float* __restrict__ X0, const float* __restrict__ X1,
    const ushort_t* __restrict__ Wb,
    float* __restrict__ O0, float* __restrict__ O1) {
  __shared__ __align__(16) unsigned Xs[64 * 64];
  int side = blockIdx.y;
  const float* Wf = side ? Wf1 : Wf0;
  const float* R = side ? X1 : X0;
  float* O = side ? O1 : O0;
  int bid = blockIdx.x;
  int b = bid >> 9, h = (bid >> 2) & 127, w0 = (bid & 3) << 6;
  int t = threadIdx.x;
  int lane = t & 63, wid = t >> 6, hi = lane >> 5, lr = lane & 31;
  int ch8 = t >> 4, pxq = t & 15;
  int c0 = ch8 * 8, wb2 = w0 + pxq * 4;
  float vv[8][4];
#pragma unroll
  for (int cc = 0; cc < 8; ++cc) {
    int c = c0 + cc;
    float4 a = *(const float4*)(Wf + (b * C_ + c) * HW_ + h * W_ + wb2);
    vv[cc][0] = a.x; vv[cc][1] = a.y; vv[cc][2] = a.z; vv[cc][3] = a.w;
  }
#pragma unroll
  for (int i = 0; i < 4; ++i) {
    int px = pxq * 4 + i;
    int cl = ch8 ^ (px & 7);
    *(uint4*)&Xs[px * 64 + cl * 4] =
        make_uint4(pk2(vv[0][i], vv[1][i]), pk2(vv[2][i], vv[3][i]),
                   pk2(vv[4][i], vv[5][i]), pk2(vv[6][i], vv[7][i]));
  }
  __syncthreads();
  f32x16 acc0 = {}, acc1 = {};
  gemm_core(Xs, Wb, lane, wid, acc0, acc1);
  int obase = wid * 32 + 4 * hi;
#pragma unroll
  for (int r = 0; r < 16; ++r) {
    int o = obase + (r & 3) + 8 * (r >> 2);
    const float* rp = R + (b * C_ + o) * HW_ + h * W_ + w0;
    float* op = O + (b * C_ + o) * HW_ + h * W_ + w0;
    op[lr] = acc0[r] + rp[lr];
    op[32 + lr] = acc1[r] + rp[32 + lr];
  }
}

// ---------------- launch ----------------
extern "C" void kernel_launch(void* const* d_in, const int* in_sizes, int n_in,
                              void* d_out, int out_size, void* d_ws, size_t ws_size,
                              hipStream_t stream) {
  const float* xl0    = (const float*)d_in[0];
  const float* xr0    = (const float*)d_in[1];
  const float* ln_l_w = (const float*)d_in[2];
  const float* ln_l_b = (const float*)d_in[3];
  const float* ln_r_w = (const float*)d_in[4];
  const float* ln_r_b = (const float*)d_in[5];
  const float* feaL_w = (const float*)d_in[6];
  const float* feaR_w = (const float*)d_in[7];
  const float* to_l_w = (const float*)d_in[8];
  const float* to_r_w = (const float*)d_in[9];
  const float* td_w   = (const float*)d_in[10];
  const float* td_b   = (const float*)d_in[11];
  const float* tp_w   = (const float*)d_in[12];
  const float* tp_b   = (const float*)d_in[13];
  const float* out_w  = (const float*)d_in[14];

  float* o0 = (float*)d_out;                 // final left; warpL lives here too
  float* o1 = o0 + TEN_;                     // final right; warpR
  unsigned* qL = (unsigned*)d_out;           // even-slot strided pairs in o0 region
  unsigned* qR = qL + TEN_;                  // in o1 region
  unsigned* bL = (unsigned*)d_ws;            // x_left bf16 pairs (compact)
  unsigned* bR = bL + P16_;
  unsigned* vL = bR + P16_;                  // V bf16 pairs (compact)
  unsigned* vR = vL + P16_;
  ushort_t* wb = (ushort_t*)(vR + P16_);
  ushort_t* wb_feaL = wb + 0 * 16384;
  ushort_t* wb_feaR = wb + 1 * 16384;
  ushort_t* wb_tol  = wb + 2 * 16384;
  ushort_t* wb_tor  = wb + 3 * 16384;
  ushort_t* wb_tp   = wb + 4 * 16384;
  ushort_t* wb_out  = wb + 5 * 16384;

  WbPack pw;
  pw.s[0] = feaL_w; pw.s[1] = feaR_w; pw.s[2] = to_l_w;
  pw.s[3] = to_r_w; pw.s[4] = tp_w;   pw.s[5] = out_w;
  pw.d[0] = wb_feaL; pw.d[1] = wb_feaR; pw.d[2] = wb_tol;
  pw.d[3] = wb_tor;  pw.d[4] = wb_tp;   pw.d[5] = wb_out;
  k_wb<<<dim3(64, 6), 256, 0, stream>>>(pw);

  // transition (fused dw3x3, split channel-pair staging) + bias + resid + LN
  k_trans<<<dim3(1024, 2), 256, 0, stream>>>(
      xl0, xr0, wb_tp, td_w, td_b, tp_b,
      ln_l_w, ln_l_b, ln_r_w, ln_r_b, bL, bR);

  // Q (shifted x_left/right) and V (shifted inputs), vectorized staging
  k_qv<<<dim3(1024, 4), 256, 0, stream>>>(
      bL, bR, xl0, xr0, wb_tol, wb_tor, wb_feaL, wb_feaR,
      qL, qR, vL, vR);

  // MFMA attention -> f32 warp (in-place over Q regions; per-block safe)
  k_attn<<<1024, 256, 0, stream>>>(qL, qR, vL, vR, o0, o1);

  // final conv + residual, in-place over warp
  k_fin<<<dim3(1024, 2), 256, 0, stream>>>(
      o0, o1, xl0, xr0, wb_out, o0, o1);
}

// Round 10
// 188.278 us; speedup vs baseline: 4.2696x; 1.0087x over previous
//
#include <hip/hip_runtime.h>

#define DEVI static __device__ __forceinline__

constexpr int B_ = 2, C_ = 128, H_ = 128, W_ = 256;
constexpr int CG_ = 32, MD_ = 96;
constexpr int HW_ = H_ * W_;        // 32768
constexpr int CHW_ = C_ * HW_;      // 4194304
constexpr int TEN_ = B_ * CHW_;     // 8388608 elements per tensor
constexpr int P16_ = TEN_ / 2;      // u32 count of a bf16-paired tensor

typedef short bf16x8 __attribute__((ext_vector_type(8)));
typedef float f32x16 __attribute__((ext_vector_type(16)));
typedef unsigned short ushort_t;

// ---------------- bf16 helpers ----------------
DEVI ushort_t f2b(float f) {
  unsigned u = __float_as_uint(f);
  return (ushort_t)((u + 0x7fffu + ((u >> 16) & 1u)) >> 16);   // RNE bf16
}
DEVI unsigned pk2(float a, float b) {
  return (unsigned)f2b(a) | ((unsigned)f2b(b) << 16);
}
DEVI float blo(unsigned u) { return __uint_as_float(u << 16); }
DEVI float bhi(unsigned u) { return __uint_as_float(u & 0xffff0000u); }
DEVI float sum8(uint4 v) {
  return blo(v.x) + bhi(v.x) + blo(v.y) + bhi(v.y) +
         blo(v.z) + bhi(v.z) + blo(v.w) + bhi(v.w);
}
DEVI int xcd_remap(int hw) { return (hw & 7) * 128 + (hw >> 3); }   // bijective, 1024%8==0

// ---------------- weight convert: Wb[o][k] bf16 ----------------
struct WbPack { const float* s[6]; ushort_t* d[6]; };

__global__ __launch_bounds__(256) void k_wb(WbPack p) {
  int m = blockIdx.y;
  int idx = blockIdx.x * 256 + threadIdx.x;
  p.d[m][idx] = f2b(p.s[m][idx]);
}

// ======== shared GEMM core (32x32x16 bf16, tile 64px x 128o) ========
// LDS Xs[px][64 u32 = 128ch bf16 pairs]; 16B cluster swizzle cl' = cl ^ (px&7).
DEVI void gemm_core(const unsigned* Xs, const ushort_t* Wb, int lane, int wid,
                    f32x16& acc0, f32x16& acc1) {
  int hi = lane >> 5, lr = lane & 31;
  bf16x8 wf[8];
  const ushort_t* wbase = Wb + (wid * 32 + lr) * 128 + hi * 8;
#pragma unroll
  for (int kk = 0; kk < 8; ++kk) wf[kk] = *(const bf16x8*)(wbase + kk * 16);
  int xsw = lr & 7;
#pragma unroll
  for (int kk = 0; kk < 8; ++kk) {
    int cl = 2 * kk + hi;
    bf16x8 x0 = *(const bf16x8*)&Xs[lr * 64 + ((cl ^ xsw) << 2)];
    bf16x8 x1 = *(const bf16x8*)&Xs[(32 + lr) * 64 + ((cl ^ xsw) << 2)];
    acc0 = __builtin_amdgcn_mfma_f32_32x32x16_bf16(wf[kk], x0, acc0, 0, 0, 0);
    acc1 = __builtin_amdgcn_mfma_f32_32x32x16_bf16(wf[kk], x1, acc1, 0, 0, 0);
  }
}

// ---------------- k_trans: UNCHANGED from R9 (verified) ----------------
__global__ __launch_bounds__(256) void k_trans(
    const float* __restrict__ X0, const float* __restrict__ X1,
    const ushort_t* __restrict__ Wb,
    const float* __restrict__ dww, const float* __restrict__ dwb,
    const float* __restrict__ cb,
    const float* __restrict__ lnw0, const float* __restrict__ lnb0,
    const float* __restrict__ lnw1, const float* __restrict__ lnb1,
    unsigned* __restrict__ O0, unsigned* __restrict__ O1) {
  __shared__ __align__(16) unsigned Xs[64 * 64];
  __shared__ float red[640];
  int side = blockIdx.y;
  const float* X = side ? X1 : X0;
  const float* lnw = side ? lnw1 : lnw0;
  const float* lnb = side ? lnb1 : lnb0;
  unsigned* O = side ? O1 : O0;
  int bid = xcd_remap(blockIdx.x);
  int b = bid >> 9, h = (bid >> 2) & 127, w0 = (bid & 3) << 6;
  int t = threadIdx.x;
  int lane = t & 63, wid = t >> 6, hi = lane >> 5, lr = lane & 31;

  int oct = t & 7, cg = t >> 3;
  int wb2 = w0 + oct * 8;
#pragma unroll
  for (int p = 0; p < 2; ++p) {        // channel pair p: channels 4cg+2p, 4cg+2p+1
    float accs[2][8];
#pragma unroll
    for (int cc = 0; cc < 2; ++cc) {
      int c = cg * 4 + p * 2 + cc;
      const float* Xp = X + (b * C_ + c) * HW_;
      const float* wp = dww + c * 9;
      float bb = dwb[c];
#pragma unroll
      for (int i = 0; i < 8; ++i) accs[cc][i] = bb;
#pragma unroll
      for (int dy = -1; dy <= 1; ++dy) {
        int hh = h + dy;
        if (hh < 0 || hh >= H_) continue;
        const float* row = Xp + hh * W_;
        float4 a = *(const float4*)(row + wb2);
        float4 bq = *(const float4*)(row + wb2 + 4);
        float vm = (wb2 > 0) ? row[wb2 - 1] : 0.f;
        float vp = (wb2 + 8 < W_) ? row[wb2 + 8] : 0.f;
        float v10[10] = {vm, a.x, a.y, a.z, a.w, bq.x, bq.y, bq.z, bq.w, vp};
        const float* wr = wp + (dy + 1) * 3;
        float tw0 = wr[0], tw1 = wr[1], tw2 = wr[2];
#pragma unroll
        for (int i = 0; i < 8; ++i) {
          accs[cc][i] += tw0 * v10[i];       // sequential v_fmac, R8 order
          accs[cc][i] += tw1 * v10[i + 1];
          accs[cc][i] += tw2 * v10[i + 2];
        }
      }
    }
    int wic = (2 * cg + p) & 3;
    int clb = cg >> 1;
#pragma unroll
    for (int k = 0; k < 8; ++k) {
      int pxl = (k + oct) & 7;
      int px = oct * 8 + pxl;
      Xs[px * 64 + (((clb ^ pxl) & 15) << 2) + wic] = pk2(accs[0][pxl], accs[1][pxl]);
    }
  }
  __syncthreads();

  f32x16 acc0 = {}, acc1 = {};
  gemm_core(Xs, Wb, lane, wid, acc0, acc1);

  int obase = wid * 32 + 4 * hi;
#pragma unroll
  for (int r = 0; r < 16; ++r) {
    int o = obase + (r & 3) + 8 * (r >> 2);
    float bb = cb[o];
    const float* rp = X + (b * C_ + o) * HW_ + h * W_ + w0;
    acc0[r] += bb + rp[lr];
    acc1[r] += bb + rp[32 + lr];
  }
  {
    float s0 = 0, s1 = 0, q0 = 0, q1 = 0;
#pragma unroll
    for (int r = 0; r < 16; ++r) {
      s0 += acc0[r]; q0 += acc0[r] * acc0[r];
      s1 += acc1[r]; q1 += acc1[r] * acc1[r];
    }
    s0 += __shfl_xor(s0, 32); q0 += __shfl_xor(q0, 32);
    s1 += __shfl_xor(s1, 32); q1 += __shfl_xor(q1, 32);
    if (hi == 0) {
      red[wid * 64 + lr] = s0;       red[wid * 64 + 32 + lr] = s1;
      red[256 + wid * 64 + lr] = q0; red[256 + wid * 64 + 32 + lr] = q1;
    }
    __syncthreads();
    if (t < 64) {
      float ss = red[t] + red[64 + t] + red[128 + t] + red[192 + t];
      float qq = red[256 + t] + red[320 + t] + red[384 + t] + red[448 + t];
      float mu = ss * (1.0f / 128.0f);
      float var = qq * (1.0f / 128.0f) - mu * mu;   // biased
      red[512 + t] = mu;
      red[576 + t] = rsqrtf(var + 1e-6f);
    }
    __syncthreads();
    float mu0 = red[512 + lr], rs0 = red[576 + lr];
    float mu1 = red[544 + lr], rs1 = red[608 + lr];
#pragma unroll
    for (int r = 0; r < 16; ++r) {
      int o = obase + (r & 3) + 8 * (r >> 2);
      float lw = lnw[o], lb2 = lnb[o];
      acc0[r] = lw * ((acc0[r] - mu0) * rs0) + lb2;
      acc1[r] = lw * ((acc1[r] - mu1) * rs1) + lb2;
    }
  }
#pragma unroll
  for (int r = 0; r < 16; r += 2) {
    int o = obase + (r & 3) + 8 * (r >> 2);
    unsigned* orow = O + (b * 64 + (o >> 1)) * HW_ + h * W_ + w0;
    orow[lr] = pk2(acc0[r], acc0[r + 1]);
    orow[32 + lr] = pk2(acc1[r], acc1[r + 1]);
  }
}

// ---------------- k_qv: UNCHANGED from R9 (verified) ----------------
__global__ __launch_bounds__(256) void k_qv(
    const unsigned* __restrict__ B0, const unsigned* __restrict__ B1,
    const float* __restrict__ X0, const float* __restrict__ X1,
    const ushort_t* __restrict__ WQ0, const ushort_t* __restrict__ WQ1,
    const ushort_t* __restrict__ WV0, const ushort_t* __restrict__ WV1,
    unsigned* __restrict__ Q0, unsigned* __restrict__ Q1,
    unsigned* __restrict__ V0, unsigned* __restrict__ V1) {
  __shared__ __align__(16) unsigned Xs[64 * 64];
  int ty = blockIdx.y;                // 0 QL, 1 QR, 2 VL, 3 VR
  int bid = xcd_remap(blockIdx.x);
  int b = bid >> 9, h = (bid >> 2) & 127, w0 = (bid & 3) << 6;
  int t = threadIdx.x;
  int lane = t & 63, wid = t >> 6, hi = lane >> 5, lr = lane & 31;
  const ushort_t* Wb = (ty == 0) ? WQ0 : (ty == 1) ? WQ1 : (ty == 2) ? WV0 : WV1;

  if (ty < 2) {
    const unsigned* S = ty ? B1 : B0;
#pragma unroll
    for (int uu = 0; uu < 4; ++uu) {
      int unit = uu * 256 + t;
      int c2u = unit >> 4, pxq = unit & 15;
      int wb2 = w0 + pxq * 4;
      int g = c2u >> 3;
      unsigned v[4];
      const unsigned* rowp = S + (b * 64 + c2u) * HW_ + h * W_;
      if (g >= 4) {
        uint4 a = *(const uint4*)(rowp + wb2);
        v[0] = a.x; v[1] = a.y; v[2] = a.z; v[3] = a.w;
      } else if (g >= 2) {
        int hh = h + (g == 2 ? 1 : -1);
        if (hh >= 0 && hh < H_) {
          uint4 a = *(const uint4*)(S + (b * 64 + c2u) * HW_ + hh * W_ + wb2);
          v[0] = a.x; v[1] = a.y; v[2] = a.z; v[3] = a.w;
        } else { v[0] = v[1] = v[2] = v[3] = 0u; }
      } else {
        int d = (g == 0) ? 1 : -1;
#pragma unroll
        for (int i = 0; i < 4; ++i) {
          int ww = wb2 + i + d;
          v[i] = (ww >= 0 && ww < W_) ? rowp[ww] : 0u;
        }
      }
#pragma unroll
      for (int i = 0; i < 4; ++i) {
        int px = pxq * 4 + i;
        Xs[px * 64 + (((c2u >> 2) ^ (px & 7)) << 2) + (c2u & 3)] = v[i];
      }
    }
  } else {
    const float* S = (ty == 2) ? X0 : X1;
    int ch8 = t >> 4, pxq = t & 15;
    int c0 = ch8 * 8, wb2 = w0 + pxq * 4;
    float vv[8][4];
#pragma unroll
    for (int cc = 0; cc < 8; ++cc) {
      int c = c0 + cc;
      int g = c >> 4;
      const float* rowp = S + (b * C_ + c) * HW_ + h * W_;
      if (g >= 4) {
        float4 a = *(const float4*)(rowp + wb2);
        vv[cc][0] = a.x; vv[cc][1] = a.y; vv[cc][2] = a.z; vv[cc][3] = a.w;
      } else if (g >= 2) {
        int hh = h + (g == 2 ? 1 : -1);
        if (hh >= 0 && hh < H_) {
          float4 a = *(const float4*)(S + (b * C_ + c) * HW_ + hh * W_ + wb2);
          vv[cc][0] = a.x; vv[cc][1] = a.y; vv[cc][2] = a.z; vv[cc][3] = a.w;
        } else { vv[cc][0] = vv[cc][1] = vv[cc][2] = vv[cc][3] = 0.f; }
      } else if (g == 0) {       // w+1 shift
        float4 a = *(const float4*)(rowp + wb2);
        float x4 = (wb2 + 4 < W_) ? rowp[wb2 + 4] : 0.f;
        vv[cc][0] = a.y; vv[cc][1] = a.z; vv[cc][2] = a.w; vv[cc][3] = x4;
      } else {                    // w-1 shift
        float4 a = *(const float4*)(rowp + wb2);
        float xm = (wb2 > 0) ? rowp[wb2 - 1] : 0.f;
        vv[cc][0] = xm; vv[cc][1] = a.x; vv[cc][2] = a.y; vv[cc][3] = a.z;
      }
    }
#pragma unroll
    for (int i = 0; i < 4; ++i) {
      int px = pxq * 4 + i;
      int cl = ch8 ^ (px & 7);
      *(uint4*)&Xs[px * 64 + cl * 4] =
          make_uint4(pk2(vv[0][i], vv[1][i]), pk2(vv[2][i], vv[3][i]),
                     pk2(vv[4][i], vv[5][i]), pk2(vv[6][i], vv[7][i]));
    }
  }
  __syncthreads();

  f32x16 acc0 = {}, acc1 = {};
  gemm_core(Xs, Wb, lane, wid, acc0, acc1);

  int obase = wid * 32 + 4 * hi;
  if (ty < 2) {
    unsigned* O = ty ? Q1 : Q0;
#pragma unroll
    for (int r = 0; r < 16; r += 2) {
      int o = obase + (r & 3) + 8 * (r >> 2);                 // even
      unsigned* orow = O + b * CHW_ + o * HW_ + h * W_ + w0;  // even-slot strided
      orow[lr] = pk2(acc0[r], acc0[r + 1]);
      orow[32 + lr] = pk2(acc1[r], acc1[r + 1]);
    }
  } else {
    unsigned* O = (ty == 2) ? V0 : V1;
#pragma unroll
    for (int r = 0; r < 16; r += 2) {
      int o = obase + (r & 3) + 8 * (r >> 2);                 // even
      unsigned* orow = O + (b * 64 + (o >> 1)) * HW_ + h * W_ + w0;
      orow[lr] = pk2(acc0[r], acc0[r + 1]);
      orow[32 + lr] = pk2(acc1[r], acc1[r + 1]);
    }
  }
}

// ============ MFMA attention (R9 core; out = bf16 px-paired, in-lane pk2) ============
DEVI bf16x8 ldfrag(const unsigned* A, int r, int cl) {
  int clp = cl ^ ((r >> 1) & 3);
  uint4 v = *(const uint4*)(A + r * 16 + clp * 4);
  return __builtin_bit_cast(bf16x8, v);
}
DEVI bf16x8 vfrag(const unsigned* Vt, int c, int ktg, int hi) {
  int jc = 2 * ktg + hi;
  int jcp = jc ^ (c & 7);
  uint4 v = *(const uint4*)(Vt + c * 128 + jcp * 4);
  return __builtin_bit_cast(bf16x8, v);
}
DEVI void stageQ16(const unsigned* __restrict__ G, unsigned* A, int t) {
  unsigned r[16];
#pragma unroll
  for (int c2 = 0; c2 < 16; ++c2) r[c2] = G[(2 * c2) * HW_ + t];
  int sw = (t >> 1) & 3;
#pragma unroll
  for (int cl = 0; cl < 4; ++cl) {
    int clp = cl ^ sw;
    *(uint4*)(A + t * 16 + clp * 4) =
        make_uint4(r[cl * 4], r[cl * 4 + 1], r[cl * 4 + 2], r[cl * 4 + 3]);
  }
}
DEVI void stageVt(const unsigned* __restrict__ G, unsigned* Vt, int t) {
  ushort_t* V16 = (ushort_t*)Vt;
#pragma unroll
  for (int c2 = 0; c2 < 16; ++c2) {
    unsigned u = G[c2 * HW_ + t];
#pragma unroll
    for (int e = 0; e < 2; ++e) {
      int c = 2 * c2 + e;
      int w16 = (c * 128 + (((t >> 3) ^ (c & 7)) << 2) + ((t >> 1) & 3)) * 2 + (t & 1);
      V16[w16] = (ushort_t)(e ? (u >> 16) : (u & 0xffffu));
    }
  }
}
DEVI void psv_comp(const unsigned* Vt, float* psv, int t) {
  int jt = t >> 5, c = t & 31;
  float s = 0.f;
#pragma unroll
  for (int q = 0; q < 4; ++q) {
    int jcp = (4 * jt + q) ^ (c & 7);
    s += sum8(*(const uint4*)(Vt + c * 128 + jcp * 4));
  }
  psv[jt * 32 + c] = s;
}

template <int DIR>
DEVI void attn_pass(const unsigned* Ql_, const unsigned* Qk_, const unsigned* Vt,
                    const float* psv, float* emr, unsigned* __restrict__ outG,
                    int wid, int lane) {
  int hi = lane >> 5, cq = lane & 31;
#pragma unroll
  for (int s = 0; s < 2; ++s) {
    int qt = 2 * wid + s;
    int q = qt * 32 + cq;
    int jt0 = DIR ? qt : (qt >= 3 ? qt - 3 : 0);
    int jt1 = DIR ? (qt <= 4 ? qt + 3 : 7) : qt;
    int nt = jt1 - jt0 + 1;                      // wave-uniform
    bf16x8 bq0 = ldfrag(Ql_, q, hi);
    bf16x8 bq1 = ldfrag(Ql_, q, hi + 2);
    f32x16 S[4];
#pragma unroll
    for (int ji = 0; ji < 4; ++ji) {
      if (ji < nt) {
        int jt = jt0 + ji;
        f32x16 d = {};
        d = __builtin_amdgcn_mfma_f32_32x32x16_bf16(
            ldfrag(Qk_, jt * 32 + cq, hi), bq0, d, 0, 0, 0);
        d = __builtin_amdgcn_mfma_f32_32x32x16_bf16(
            ldfrag(Qk_, jt * 32 + cq, hi + 2), bq1, d, 0, 0, 0);
        S[ji] = d;
      }
    }
    float m = 0.f;
#pragma unroll
    for (int ji = 0; ji < 4; ++ji) if (ji < nt) {
      int jb = (jt0 + ji) * 32 + 4 * hi;
#pragma unroll
      for (int r = 0; r < 16; ++r) {
        int j = jb + (r & 3) + 8 * (r >> 2);
        bool act = DIR ? (j >= q && j <= q + MD_) : (j <= q && j >= q - MD_);
        float v = act ? S[ji][r] : 0.f;
        S[ji][r] = v;
        m = fmaxf(m, v);
      }
    }
    m = fmaxf(m, __shfl_xor(m, 32));
    float em_ = __expf(-m);
    float lsum = 0.f;
#pragma unroll
    for (int ji = 0; ji < 4; ++ji) if (ji < nt) {
#pragma unroll
      for (int r = 0; r < 16; ++r) {
        float e = __expf(S[ji][r] - m);
        S[ji][r] = e;
        lsum += e;
      }
    }
    lsum += __shfl_xor(lsum, 32);
    lsum += (float)((8 - nt) * 32) * em_;
    float rl = 1.f / lsum;
    if (hi == 0) { emr[qt * 32 + cq] = em_; emr[256 + qt * 32 + cq] = rl; }
    f32x16 acc = {};
#pragma unroll
    for (int ji = 0; ji < 4; ++ji) if (ji < nt) {
      int jt = jt0 + ji;
      unsigned x[8], ox[8];
#pragma unroll
      for (int w2 = 0; w2 < 8; ++w2) x[w2] = pk2(S[ji][2 * w2], S[ji][2 * w2 + 1]);
#pragma unroll
      for (int w2 = 0; w2 < 8; ++w2) ox[w2] = __shfl_xor(x[w2], 32);
#pragma unroll
      for (int hf = 0; hf < 2; ++hf) {
        unsigned w0 = hi ? ox[4 * hf + 2] : x[4 * hf + 0];
        unsigned w1 = hi ? ox[4 * hf + 3] : x[4 * hf + 1];
        unsigned w2_ = hi ? x[4 * hf + 2] : ox[4 * hf + 0];
        unsigned w3 = hi ? x[4 * hf + 3] : ox[4 * hf + 1];
        uint4 aw = make_uint4(w0, w1, w2_, w3);
        acc = __builtin_amdgcn_mfma_f32_32x32x16_bf16(
            __builtin_bit_cast(bf16x8, aw), vfrag(Vt, cq, 2 * jt + hf, hi),
            acc, 0, 0, 0);
      }
    }
    float Rv = 0.f;
#pragma unroll
    for (int jt = 0; jt < 8; ++jt)
      if (jt < jt0 || jt > jt1) Rv += psv[jt * 32 + cq];
    // out: bf16 px-paired [c][HW/2]; rows qr0 (even), qr0+1 are IN-LANE (acc[r], acc[r+1])
#pragma unroll
    for (int r = 0; r < 16; r += 2) {
      int qr0 = (r & 3) + 8 * (r >> 2) + 4 * hi;               // even
      float v0 = (acc[r] + emr[qt * 32 + qr0] * Rv) * emr[256 + qt * 32 + qr0];
      float v1 = (acc[r + 1] + emr[qt * 32 + qr0 + 1] * Rv) * emr[256 + qt * 32 + qr0 + 1];
      outG[cq * (HW_ / 2) + ((qt * 32 + qr0) >> 1)] = pk2(v0, v1);
    }
  }
}

__global__ __launch_bounds__(256) void k_attn(
    const unsigned* __restrict__ qL, const unsigned* __restrict__ qR,
    const unsigned* __restrict__ vL, const unsigned* __restrict__ vR,
    unsigned* __restrict__ wL, unsigned* __restrict__ wR) {
  __shared__ __align__(16) unsigned Ql[4096];
  __shared__ __align__(16) unsigned Qr[4096];
  __shared__ __align__(16) unsigned Vt[4096];
  __shared__ float psv[256];
  __shared__ float emr[512];
  int t = threadIdx.x;
  int bid = blockIdx.x;
  int b = bid >> 9, k4 = (bid >> 7) & 3, h = bid & 127;
  int qoff = b * CHW_ + (k4 * CG_) * HW_ + h * W_;             // even-slot strided base
  int voff = (b * 64 + k4 * 16) * HW_ + h * W_;                // compact pair base (V in)
  int woff = (b * C_ + k4 * CG_) * (HW_ / 2) + h * (W_ / 2);   // px-paired base (warp out)
  stageQ16(qL + qoff, Ql, t);
  stageQ16(qR + qoff, Qr, t);
  stageVt(vR + voff, Vt, t);
  __syncthreads();
  psv_comp(Vt, psv, t);
  __syncthreads();
  int wid = t >> 6, lane = t & 63;
  attn_pass<0>(Ql, Qr, Vt, psv, emr, wL + woff, wid, lane);
  __syncthreads();
  stageVt(vL + voff, Vt, t);
  __syncthreads();
  psv_comp(Vt, psv, t);
  __syncthreads();
  attn_pass<1>(Qr, Ql, Vt, psv, emr, wR + woff, wid, lane);
}

// ---------------- k_fin: final conv + residual -> f32 out (px-paired bf16 warp in) ----------------
__global__ __launch_bounds__(256) void k_fin(
    const unsigned* __restrict__ W0, const unsigned* __restrict__ W1,
    const float* __restrict__ X0, const float* __restrict__ X1,
    const ushort_t* __restrict__ Wb,
    float* __restrict__ O0, float* __restrict__ O1) {
  __shared__ __align__(16) unsigned Xs[64 * 64];
  int side = blockIdx.y;
  const unsigned* Wsrc = side ? W1 : W0;
  const float* R = side ? X1 : X0;
  float* O = side ? O1 : O0;
  int bid = blockIdx.x;
  int b = bid >> 9, h = (bid >> 2) & 127, w0 = (bid & 3) << 6;
  int t = threadIdx.x;
  int lane = t & 63, wid = t >> 6, hi = lane >> 5, lr = lane & 31;
  // stage: 2048 units = 64 cpairs x 32 pxpairs; 2 coalesced u32 reads -> pair-transpose -> 2 LDS words
#pragma unroll
  for (int uu = 0; uu < 8; ++uu) {
    int unit = uu * 256 + t;
    int cp = unit >> 5;             // channel-pair 0..63
    int jp = unit & 31;             // px-pair 0..31
    const unsigned* base = Wsrc + h * (W_ / 2) + (w0 >> 1) + jp;
    unsigned lo = base[(b * C_ + 2 * cp) * (HW_ / 2)];       // ch 2cp:   px 2jp, 2jp+1
    unsigned hi2 = base[(b * C_ + 2 * cp + 1) * (HW_ / 2)];  // ch 2cp+1: px 2jp, 2jp+1
    unsigned w0p = (lo & 0xffffu) | (hi2 << 16);             // px 2jp:   (ch2cp, ch2cp+1)
    unsigned w1p = (lo >> 16) | (hi2 & 0xffff0000u);         // px 2jp+1
    int px0 = 2 * jp, px1 = 2 * jp + 1;
    Xs[px0 * 64 + (((cp >> 2) ^ (px0 & 7)) << 2) + (cp & 3)] = w0p;
    Xs[px1 * 64 + (((cp >> 2) ^ (px1 & 7)) << 2) + (cp & 3)] = w1p;
  }
  __syncthreads();
  f32x16 acc0 = {}, acc1 = {};
  gemm_core(Xs, Wb, lane, wid, acc0, acc1);
  int obase = wid * 32 + 4 * hi;
#pragma unroll
  for (int r = 0; r < 16; ++r) {
    int o = obase + (r & 3) + 8 * (r >> 2);
    const float* rp = R + (b * C_ + o) * HW_ + h * W_ + w0;
    float* op = O + (b * C_ + o) * HW_ + h * W_ + w0;
    op[lr] = acc0[r] + rp[lr];
    op[32 + lr] = acc1[r] + rp[32 + lr];
  }
}

// ---------------- launch ----------------
extern "C" void kernel_launch(void* const* d_in, const int* in_sizes, int n_in,
                              void* d_out, int out_size, void* d_ws, size_t ws_size,
                              hipStream_t stream) {
  const float* xl0    = (const float*)d_in[0];
  const float* xr0    = (const float*)d_in[1];
  const float* ln_l_w = (const float*)d_in[2];
  const float* ln_l_b = (const float*)d_in[3];
  const float* ln_r_w = (const float*)d_in[4];
  const float* ln_r_b = (const float*)d_in[5];
  const float* feaL_w = (const float*)d_in[6];
  const float* feaR_w = (const float*)d_in[7];
  const float* to_l_w = (const float*)d_in[8];
  const float* to_r_w = (const float*)d_in[9];
  const float* td_w   = (const float*)d_in[10];
  const float* td_b   = (const float*)d_in[11];
  const float* tp_w   = (const float*)d_in[12];
  const float* tp_b   = (const float*)d_in[13];
  const float* out_w  = (const float*)d_in[14];

  float* o0 = (float*)d_out;                 // final left (Q scratch first)
  float* o1 = o0 + TEN_;                     // final right
  unsigned* qL = (unsigned*)d_out;           // even-slot strided pairs in o0 region
  unsigned* qR = qL + TEN_;                  // in o1 region
  unsigned* bL = (unsigned*)d_ws;            // x_left bf16 pairs; later warpL (px-paired)
  unsigned* bR = bL + P16_;                  // x_right; later warpR
  unsigned* vL = bR + P16_;                  // V bf16 pairs (compact)
  unsigned* vR = vL + P16_;
  ushort_t* wb = (ushort_t*)(vR + P16_);
  ushort_t* wb_feaL = wb + 0 * 16384;
  ushort_t* wb_feaR = wb + 1 * 16384;
  ushort_t* wb_tol  = wb + 2 * 16384;
  ushort_t* wb_tor  = wb + 3 * 16384;
  ushort_t* wb_tp   = wb + 4 * 16384;
  ushort_t* wb_out  = wb + 5 * 16384;

  WbPack pw;
  pw.s[0] = feaL_w; pw.s[1] = feaR_w; pw.s[2] = to_l_w;
  pw.s[3] = to_r_w; pw.s[4] = tp_w;   pw.s[5] = out_w;
  pw.d[0] = wb_feaL; pw.d[1] = wb_feaR; pw.d[2] = wb_tol;
  pw.d[3] = wb_tor;  pw.d[4] = wb_tp;   pw.d[5] = wb_out;
  k_wb<<<dim3(64, 6), 256, 0, stream>>>(pw);

  // transition (fused dw3x3) + bias + resid + LN -> bf16 x_left/x_right
  k_trans<<<dim3(1024, 2), 256, 0, stream>>>(
      xl0, xr0, wb_tp, td_w, td_b, tp_b,
      ln_l_w, ln_l_b, ln_r_w, ln_r_b, bL, bR);

  // Q (shifted x_left/right) and V (shifted inputs), vectorized staging
  k_qv<<<dim3(1024, 4), 256, 0, stream>>>(
      bL, bR, xl0, xr0, wb_tol, wb_tor, wb_feaL, wb_feaR,
      qL, qR, vL, vR);

  // MFMA attention -> bf16 px-paired warp into bL/bR (dead after k_qv)
  k_attn<<<1024, 256, 0, stream>>>(qL, qR, vL, vR, bL, bR);

  // final conv + residual -> f32 outputs (overwrites Q scratch in d_out)
  k_fin<<<dim3(1024, 2), 256, 0, stream>>>(
      bL, bR, xl0, xr0, wb_out, o0, o1);
}